// Round 1
// baseline (916.926 us; speedup 1.0000x reference)
//
#include <hip/hip_runtime.h>

#define NDIM 1024
#define MB (1ull<<20)

using f32x4  = __attribute__((ext_vector_type(4))) float;
using bf16x8 = __attribute__((ext_vector_type(8))) __bf16;
using u16x8  = __attribute__((ext_vector_type(8))) unsigned short;

__device__ __forceinline__ float bf2f(unsigned short u){
  union{unsigned int i; float f;} x; x.i = ((unsigned int)u)<<16; return x.f;
}
__device__ __forceinline__ unsigned short f2bf(float f){
  union{float fl; unsigned int i;} u; u.fl = f;
  unsigned int x = u.i;
  return (unsigned short)((x + 0x7fffu + ((x>>16)&1u)) >> 16);
}

// ---------------- small kernels ----------------

// x (f32) -> hi/lo bf16 split
__global__ void k_split_x(const float* __restrict__ x, unsigned short* __restrict__ hi,
                          unsigned short* __restrict__ lo){
  size_t idx = ((size_t)blockIdx.x*256 + threadIdx.x)*4;
  float4 v = *(const float4*)(x+idx);
  float vv[4] = {v.x, v.y, v.z, v.w};
  ushort4 h, l;
  unsigned short* hp = (unsigned short*)&h;
  unsigned short* lp = (unsigned short*)&l;
  #pragma unroll
  for (int s=0;s<4;s++){
    unsigned short hb = f2bf(vv[s]);
    hp[s] = hb;
    lp[s] = f2bf(vv[s] - bf2f(hb));
  }
  *(ushort4*)(hi+idx) = h;
  *(ushort4*)(lo+idx) = l;
}

// Wb [1024(c)][2048(d)] f32 -> WbT [2048(d)][1024(c)] hi/lo bf16
__global__ void k_trans_split(const float* __restrict__ Wb, unsigned short* __restrict__ hi,
                              unsigned short* __restrict__ lo){
  __shared__ float t[32][33];
  int bd = blockIdx.x, bc = blockIdx.y;
  int tx = threadIdx.x, ty = threadIdx.y;
  #pragma unroll
  for (int r=0;r<4;r++){
    int c = bc*32 + ty + r*8;
    t[ty+r*8][tx] = Wb[(size_t)c*2048 + bd*32 + tx];
  }
  __syncthreads();
  #pragma unroll
  for (int r=0;r<4;r++){
    int d = bd*32 + ty + r*8, c = bc*32 + tx;
    float v = t[tx][ty+r*8];
    unsigned short h = f2bf(v);
    hi[(size_t)d*1024 + c] = h;
    lo[(size_t)d*1024 + c] = f2bf(v - bf2f(h));
  }
}

// W_embed [j][c][d][k] f32 -> WT [z=j*2+k][d][c] bf16
__global__ void k_wt(const float* __restrict__ W, unsigned short* __restrict__ WT){
  __shared__ float t[32][33];
  int z = blockIdx.z; int j = z>>1, k = z&1;
  int bd = blockIdx.x, bc = blockIdx.y;
  int tx = threadIdx.x, ty = threadIdx.y;
  #pragma unroll
  for (int r=0;r<4;r++){
    int c = bc*32 + ty + r*8, d = bd*32 + tx;
    t[ty+r*8][tx] = W[(((size_t)j*512 + c)*512 + d)*2 + k];
  }
  __syncthreads();
  #pragma unroll
  for (int r=0;r<4;r++){
    int d = bd*32 + ty + r*8, c = bc*32 + tx;
    WT[((size_t)z*512 + d)*512 + c] = f2bf(t[tx][ty+r*8]);
  }
}

// row softmax with diag mask: S_bf16[z][c][b] -> A bf16, M = I + alpha*A (f32)
__global__ void k_softmax(const unsigned short* __restrict__ S, unsigned short* __restrict__ A,
                          float* __restrict__ M){
  int z = blockIdx.y, c = blockIdx.x, t = threadIdx.x;
  const unsigned short* row = S + ((size_t)z*NDIM + c)*NDIM;
  __shared__ float red[256];
  float v[4];
  float mx = -1e30f;
  #pragma unroll
  for (int s=0;s<4;s++){
    int b = t + s*256;
    float x = bf2f(row[b]);
    if (b==c) x = -1e30f;
    v[s] = x; mx = fmaxf(mx, x);
  }
  red[t]=mx; __syncthreads();
  for (int o=128;o>0;o>>=1){ if (t<o) red[t]=fmaxf(red[t],red[t+o]); __syncthreads(); }
  mx = red[0]; __syncthreads();
  float e[4]; float sum=0.f;
  #pragma unroll
  for (int s=0;s<4;s++){ e[s] = __expf(v[s]-mx); sum += e[s]; }
  red[t]=sum; __syncthreads();
  for (int o=128;o>0;o>>=1){ if (t<o) red[t]+=red[t+o]; __syncthreads(); }
  sum = red[0];
  float inv = 1.0f/sum;
  unsigned short* Ar = A + ((size_t)z*NDIM + c)*NDIM;
  float* Mr = M + ((size_t)z*NDIM + c)*NDIM;
  #pragma unroll
  for (int s=0;s<4;s++){
    int b = t + s*256;
    float a = e[s]*inv;
    Ar[b] = f2bf(a);
    Mr[b] = 0.1f*a + ((b==c)?1.0f:0.0f);
  }
}

// A[z][c][b] -> AT[z][b][c], bf16 transpose
__global__ void k_transb(const unsigned short* __restrict__ A, unsigned short* __restrict__ AT){
  __shared__ unsigned short t[64][65];
  int z = blockIdx.z, bb = blockIdx.x, bc = blockIdx.y;
  int tx = threadIdx.x, ty = threadIdx.y; // (64,4)
  const unsigned short* Az = A + (size_t)z*NDIM*NDIM;
  #pragma unroll
  for (int r=0;r<16;r++){
    int c = bc*64 + ty + r*4;
    t[ty+r*4][tx] = Az[(size_t)c*NDIM + bb*64 + tx];
  }
  __syncthreads();
  unsigned short* Tz = AT + (size_t)z*NDIM*NDIM;
  #pragma unroll
  for (int r=0;r<16;r++){
    int b = bb*64 + ty + r*4;
    Tz[(size_t)b*NDIM + bc*64 + tx] = t[tx][ty+r*4];
  }
}

// Aan_bf16 = bf16(0.9 * M)
__global__ void k_mcvt(const float* __restrict__ M, unsigned short* __restrict__ out){
  size_t idx = ((size_t)blockIdx.x*256 + threadIdx.x)*4;
  float4 v = *(const float4*)(M+idx);
  ushort4 o;
  o.x = f2bf(0.9f*v.x); o.y = f2bf(0.9f*v.y); o.z = f2bf(0.9f*v.z); o.w = f2bf(0.9f*v.w);
  *(ushort4*)(out+idx) = o;
}

// ---------------- bf16 NT GEMM: C[M,N] = scale * A[M,K] * B[N,K]^T (+epilogues) ----------------

struct GemmP {
  const unsigned short* A; const unsigned short* B;
  long long sA, sB;           // z-strides in elements
  int zShiftA, zShiftB;       // z index = z >> shift
  int lda, ldb;
  int K, tilesN;
  float* Cf; long long sC; int ldc; float beta;
  unsigned short* Cb; long long sCb; int ldcb;
  float* Madd;                // EPI3: += scale2 * acc (uses sC/ldc)
  const unsigned short* Sroot;// EPI4 addend root (uses sA/lda)
  const float* bias;          // EPI2 per-z bias
  float* outp;                // EPI4/5 output root
  float scale, scale2;
};

template<int EPI>
__global__ __launch_bounds__(256) void k_gemm(GemmP p){
  const int z = blockIdx.y;
  const int tm = blockIdx.x / p.tilesN;
  const int tn = blockIdx.x % p.tilesN;
  int jj=0, ii=0, kk=0;
  const unsigned short *Ap, *Bp;
  if (EPI==4 || EPI==5){
    jj = z>>3; ii = (z>>1)&3; kk = z&1;
    Ap = p.A + (size_t)(jj*2+kk)*(size_t)p.sA;
    Bp = p.B + (size_t)(ii*2+kk)*(size_t)p.sB;
  } else {
    Ap = p.A + (size_t)(z>>p.zShiftA)*(size_t)p.sA;
    Bp = p.B + (size_t)(z>>p.zShiftB)*(size_t)p.sB;
  }
  __shared__ unsigned short As[128*40];
  __shared__ unsigned short Bs[128*40];
  const int t = threadIdx.x;
  const int lane = t & 63;
  const int w = t >> 6;
  const int wm = w >> 1, wn = w & 1;
  const int srow = t >> 1, shalf = t & 1;

  f32x4 acc[4][4];
  #pragma unroll
  for (int m=0;m<4;m++)
    #pragma unroll
    for (int n=0;n<4;n++)
      acc[m][n] = (f32x4)(0.0f);

  const unsigned short* ga = Ap + (size_t)(tm*128 + srow)*p.lda + shalf*16;
  const unsigned short* gb = Bp + (size_t)(tn*128 + srow)*p.ldb + shalf*16;
  const int ldsoff = srow*40 + shalf*16;

  for (int k0=0; k0<p.K; k0+=32){
    u16x8 a0 = *(const u16x8*)(ga);
    u16x8 a1 = *(const u16x8*)(ga+8);
    u16x8 b0 = *(const u16x8*)(gb);
    u16x8 b1 = *(const u16x8*)(gb+8);
    ga += 32; gb += 32;
    __syncthreads();
    *(u16x8*)&As[ldsoff]   = a0; *(u16x8*)&As[ldsoff+8] = a1;
    *(u16x8*)&Bs[ldsoff]   = b0; *(u16x8*)&Bs[ldsoff+8] = b1;
    __syncthreads();
    const int rb = lane & 15, g = lane >> 4;
    bf16x8 af[4], bfr[4];
    #pragma unroll
    for (int m=0;m<4;m++) af[m]  = *(const bf16x8*)&As[(wm*64 + m*16 + rb)*40 + g*8];
    #pragma unroll
    for (int n=0;n<4;n++) bfr[n] = *(const bf16x8*)&Bs[(wn*64 + n*16 + rb)*40 + g*8];
    #pragma unroll
    for (int m=0;m<4;m++)
      #pragma unroll
      for (int n=0;n<4;n++)
        acc[m][n] = __builtin_amdgcn_mfma_f32_16x16x32_bf16(af[m], bfr[n], acc[m][n], 0, 0, 0);
  }

  const int rl = (lane>>4)*4;
  const int cl = lane & 15;
  const int row0 = tm*128 + wm*64;
  const int col0 = tn*128 + wn*64;
  #pragma unroll
  for (int m=0;m<4;m++){
    #pragma unroll
    for (int n=0;n<4;n++){
      #pragma unroll
      for (int r=0;r<4;r++){
        const int row = row0 + m*16 + rl + r;
        const int col = col0 + n*16 + cl;
        float v = acc[m][n][r];
        if (EPI==0){
          float* c = p.Cf + (size_t)z*p.sC + (size_t)row*p.ldc + col;
          float prev = (p.beta != 0.0f) ? *c : 0.0f;
          *c = p.scale*v + p.beta*prev;
        } else if (EPI==1){
          float* c = p.Cf + (size_t)z*p.sC + (size_t)row*p.ldc + col;
          float nv = p.scale*v + p.beta*(*c);
          *c = nv;
          p.Cb[(size_t)z*p.sCb + (size_t)row*p.ldcb + col] = f2bf(nv);
        } else if (EPI==2){
          float nv = p.scale*v + (p.bias ? p.bias[z] : 0.0f);
          p.Cb[(size_t)z*p.sCb + (size_t)row*p.ldcb + col] = f2bf(nv);
        } else if (EPI==3){
          p.Cb[(size_t)z*p.sCb + (size_t)row*p.ldcb + col] = f2bf(v);
          float* mp = p.Madd + (size_t)z*p.sC + (size_t)row*p.ldc + col;
          *mp += p.scale2 * v;
        } else if (EPI==4){
          float add = p.scale2 * bf2f(p.Sroot[(size_t)(jj*2+kk)*(size_t)p.sA + (size_t)row*p.lda + col]);
          size_t ob = (size_t)(jj*4+ii)*(2ull*NDIM*NDIM)*2 + (size_t)kk;
          p.outp[ob + ((size_t)row*NDIM + col)*2] = p.scale*v + add;
        } else if (EPI==5){
          size_t ob = (size_t)(jj*4+ii)*(2ull*NDIM*NDIM)*2 + (size_t)kk;
          p.outp[ob + ((size_t)((size_t)NDIM*NDIM + (size_t)row*NDIM + col))*2] = p.scale*v;
        }
      }
    }
  }
}

// ---------------- host ----------------

extern "C" void kernel_launch(void* const* d_in, const int* in_sizes, int n_in,
                              void* d_out, int out_size, void* d_ws, size_t ws_size,
                              hipStream_t stream){
  (void)in_sizes; (void)n_in; (void)out_size; (void)ws_size;
  const float* x  = (const float*)d_in[0];
  const float* Wb = (const float*)d_in[1];
  const float* We = (const float*)d_in[2];
  const float* be = (const float*)d_in[3];
  float* out = (float*)d_out;
  char* ws = (char*)d_ws;

  // arena (overlaid by liveness):
  unsigned short* Abuf  = (unsigned short*)(ws + 0);        // 16 MB (after feats phase)
  unsigned short* xhi   = (unsigned short*)(ws + 0);        // 2 MB
  unsigned short* xlo   = (unsigned short*)(ws + 2*MB);     // 2 MB
  unsigned short* wbth  = (unsigned short*)(ws + 4*MB);     // 4 MB
  unsigned short* wbtl  = (unsigned short*)(ws + 8*MB);     // 4 MB
  float*          featf = (float*)(ws + 12*MB);             // 8 MB
  unsigned short* Pa    = (unsigned short*)(ws + 20*MB);    // 16 MB (after S phase)
  unsigned short* featb = (unsigned short*)(ws + 20*MB);    // 4 MB
  unsigned short* WT    = (unsigned short*)(ws + 24*MB);    // 4 MB
  unsigned short* Tb    = (unsigned short*)(ws + 28*MB);    // 8 MB
  unsigned short* Sb    = (unsigned short*)(ws + 36*MB);    // 16 MB
  unsigned short* ATb   = (unsigned short*)(ws + 52*MB);    // 16 MB
  float*          Mf    = (float*)(ws + 68*MB);             // 32 MB
  unsigned short* Pb    = (unsigned short*)(ws + 100*MB);   // 16 MB

  // 1. splits / transposes of weights
  k_split_x<<<dim3(1024), dim3(256), 0, stream>>>(x, xhi, xlo);
  k_trans_split<<<dim3(64,32), dim3(32,8), 0, stream>>>(Wb, wbth, wbtl);
  k_wt<<<dim3(16,16,8), dim3(32,8), 0, stream>>>(We, WT);

  GemmP p{};
  p.ldc = 0; p.ldcb = 0;

  // 2. feats = x @ Wb  (split: hi*hi + hi*lo + lo*hi), M=1024 N=2048 K=1024
  auto feats_launch = [&](const unsigned short* Aop, const unsigned short* Bop, float beta, bool last){
    GemmP q{};
    q.A = Aop; q.B = Bop; q.sA = 0; q.sB = 0; q.zShiftA = 0; q.zShiftB = 0;
    q.lda = 1024; q.ldb = 1024; q.K = 1024; q.tilesN = 16;
    q.Cf = featf; q.sC = 0; q.ldc = 2048; q.beta = beta;
    q.Cb = featb; q.sCb = 0; q.ldcb = 2048;
    q.scale = 1.0f; q.scale2 = 0.0f;
    if (last) k_gemm<1><<<dim3(8*16,1), dim3(256), 0, stream>>>(q);
    else      k_gemm<0><<<dim3(8*16,1), dim3(256), 0, stream>>>(q);
  };
  feats_launch(xhi, wbth, 0.0f, false);
  feats_launch(xhi, wbtl, 1.0f, false);
  feats_launch(xlo, wbth, 1.0f, true);

  // 3. T[z] = xb_j @ WT_z^T   (z=j*2+k), M=1024 N=512 K=512
  {
    GemmP q{};
    q.A = featb; q.sA = 512; q.zShiftA = 1; q.lda = 2048;
    q.B = WT;    q.sB = (long long)512*512; q.zShiftB = 0; q.ldb = 512;
    q.K = 512; q.tilesN = 4;
    q.Cb = Tb; q.sCb = (long long)1024*512; q.ldcb = 512;
    q.bias = nullptr; q.scale = 1.0f;
    k_gemm<2><<<dim3(8*4,8), dim3(256), 0, stream>>>(q);
  }

  // 4. S[z] = T[z] @ xb_j^T + b_embed[z], M=1024 N=1024 K=512
  {
    GemmP q{};
    q.A = Tb;    q.sA = (long long)1024*512; q.zShiftA = 0; q.lda = 512;
    q.B = featb; q.sB = 512; q.zShiftB = 1; q.ldb = 2048;
    q.K = 512; q.tilesN = 8;
    q.Cb = Sb; q.sCb = (long long)NDIM*NDIM; q.ldcb = 1024;
    q.bias = be; q.scale = 1.0f;
    k_gemm<2><<<dim3(8*8,8), dim3(256), 0, stream>>>(q);
  }

  // 5. softmax -> A, M = I + alpha*A ; then AT
  k_softmax<<<dim3(1024,8), dim3(256), 0, stream>>>(Sb, Abuf, Mf);
  k_transb<<<dim3(16,16,8), dim3(64,4), 0, stream>>>(Abuf, ATb);

  // 6. Neumann: P_t = P_{t-1} @ A  (NT with AT), M += alpha^t * P_t, t=2..6
  auto neumann = [&](const unsigned short* Aop, unsigned short* dst, float a_t){
    GemmP q{};
    q.A = Aop; q.sA = (long long)NDIM*NDIM; q.zShiftA = 0; q.lda = 1024;
    q.B = ATb; q.sB = (long long)NDIM*NDIM; q.zShiftB = 0; q.ldb = 1024;
    q.K = 1024; q.tilesN = 8;
    q.Cb = dst; q.sCb = (long long)NDIM*NDIM; q.ldcb = 1024;
    q.Madd = Mf; q.sC = (long long)NDIM*NDIM; q.ldc = 1024;
    q.scale = 1.0f; q.scale2 = a_t;
    k_gemm<3><<<dim3(8*8,8), dim3(256), 0, stream>>>(q);
  };
  neumann(Abuf, Pa, 1e-2f);
  neumann(Pa,   Pb, 1e-3f);
  neumann(Pb,   Pa, 1e-4f);
  neumann(Pa,   Pb, 1e-5f);
  neumann(Pb,   Pa, 1e-6f);

  // 7. Aan_bf16 = bf16(0.9 * M)  (into Pb)
  k_mcvt<<<dim3(8192), dim3(256), 0, stream>>>(Mf, Pb);

  // 8. one[j,i,a,c,k] = 0.1 * (S_jk @ A_ik^T)[a,c] + 0.9 * S_jk[a,c]
  {
    GemmP q{};
    q.A = Sb;   q.sA = (long long)NDIM*NDIM; q.lda = 1024;
    q.B = Abuf; q.sB = (long long)NDIM*NDIM; q.ldb = 1024;
    q.K = 1024; q.tilesN = 8;
    q.Sroot = Sb; q.outp = out;
    q.scale = 0.1f; q.scale2 = 0.9f;
    k_gemm<4><<<dim3(8*8,32), dim3(256), 0, stream>>>(q);
  }
  // 9. ana[j,i,a,c,k] = (S_jk @ Aan_ik^T)[a,c]   (0.9 already folded into Aan)
  {
    GemmP q{};
    q.A = Sb; q.sA = (long long)NDIM*NDIM; q.lda = 1024;
    q.B = Pb; q.sB = (long long)NDIM*NDIM; q.ldb = 1024;
    q.K = 1024; q.tilesN = 8;
    q.outp = out;
    q.scale = 1.0f; q.scale2 = 0.0f;
    k_gemm<5><<<dim3(8*8,32), dim3(256), 0, stream>>>(q);
  }
}

// Round 2
// 873.830 us; speedup vs baseline: 1.0493x; 1.0493x over previous
//
#include <hip/hip_runtime.h>

#define NDIM 1024
#define MB (1ull<<20)

using f32x4  = __attribute__((ext_vector_type(4))) float;
using bf16x8 = __attribute__((ext_vector_type(8))) __bf16;
using u16x8  = __attribute__((ext_vector_type(8))) unsigned short;

__device__ __forceinline__ float bf2f(unsigned short u){
  union{unsigned int i; float f;} x; x.i = ((unsigned int)u)<<16; return x.f;
}
__device__ __forceinline__ unsigned short f2bf(float f){
  union{float fl; unsigned int i;} u; u.fl = f;
  unsigned int x = u.i;
  return (unsigned short)((x + 0x7fffu + ((x>>16)&1u)) >> 16);
}

// async global->LDS, 16B per lane. Dest must be wave-uniform base; HW adds lane*16.
__device__ __forceinline__ void gload16(const unsigned short* g, unsigned short* l){
  __builtin_amdgcn_global_load_lds(
      (const __attribute__((address_space(1))) void*)g,
      (__attribute__((address_space(3))) void*)l,
      16, 0, 0);
}

// ---------------- small kernels ----------------

// x (f32) -> hi/lo bf16 split
__global__ void k_split_x(const float* __restrict__ x, unsigned short* __restrict__ hi,
                          unsigned short* __restrict__ lo){
  size_t idx = ((size_t)blockIdx.x*256 + threadIdx.x)*4;
  float4 v = *(const float4*)(x+idx);
  float vv[4] = {v.x, v.y, v.z, v.w};
  ushort4 h, l;
  unsigned short* hp = (unsigned short*)&h;
  unsigned short* lp = (unsigned short*)&l;
  #pragma unroll
  for (int s=0;s<4;s++){
    unsigned short hb = f2bf(vv[s]);
    hp[s] = hb;
    lp[s] = f2bf(vv[s] - bf2f(hb));
  }
  *(ushort4*)(hi+idx) = h;
  *(ushort4*)(lo+idx) = l;
}

// Wb [1024(c)][2048(d)] f32 -> WbT [2048(d)][1024(c)] hi/lo bf16
__global__ void k_trans_split(const float* __restrict__ Wb, unsigned short* __restrict__ hi,
                              unsigned short* __restrict__ lo){
  __shared__ float t[32][33];
  int bd = blockIdx.x, bc = blockIdx.y;
  int tx = threadIdx.x, ty = threadIdx.y;
  #pragma unroll
  for (int r=0;r<4;r++){
    int c = bc*32 + ty + r*8;
    t[ty+r*8][tx] = Wb[(size_t)c*2048 + bd*32 + tx];
  }
  __syncthreads();
  #pragma unroll
  for (int r=0;r<4;r++){
    int d = bd*32 + ty + r*8, c = bc*32 + tx;
    float v = t[tx][ty+r*8];
    unsigned short h = f2bf(v);
    hi[(size_t)d*1024 + c] = h;
    lo[(size_t)d*1024 + c] = f2bf(v - bf2f(h));
  }
}

// W_embed [j][c][d][k] f32 -> WT [z=j*2+k][d][c] bf16
__global__ void k_wt(const float* __restrict__ W, unsigned short* __restrict__ WT){
  __shared__ float t[32][33];
  int z = blockIdx.z; int j = z>>1, k = z&1;
  int bd = blockIdx.x, bc = blockIdx.y;
  int tx = threadIdx.x, ty = threadIdx.y;
  #pragma unroll
  for (int r=0;r<4;r++){
    int c = bc*32 + ty + r*8, d = bd*32 + tx;
    t[ty+r*8][tx] = W[(((size_t)j*512 + c)*512 + d)*2 + k];
  }
  __syncthreads();
  #pragma unroll
  for (int r=0;r<4;r++){
    int d = bd*32 + ty + r*8, c = bc*32 + tx;
    WT[((size_t)z*512 + d)*512 + c] = f2bf(t[tx][ty+r*8]);
  }
}

// row softmax with diag mask: S_bf16[z][c][b] -> A bf16, M = I + alpha*A (f32)
__global__ void k_softmax(const unsigned short* __restrict__ S, unsigned short* __restrict__ A,
                          float* __restrict__ M){
  int z = blockIdx.y, c = blockIdx.x, t = threadIdx.x;
  const unsigned short* row = S + ((size_t)z*NDIM + c)*NDIM;
  __shared__ float red[256];
  float v[4];
  float mx = -1e30f;
  #pragma unroll
  for (int s=0;s<4;s++){
    int b = t + s*256;
    float x = bf2f(row[b]);
    if (b==c) x = -1e30f;
    v[s] = x; mx = fmaxf(mx, x);
  }
  red[t]=mx; __syncthreads();
  for (int o=128;o>0;o>>=1){ if (t<o) red[t]=fmaxf(red[t],red[t+o]); __syncthreads(); }
  mx = red[0]; __syncthreads();
  float e[4]; float sum=0.f;
  #pragma unroll
  for (int s=0;s<4;s++){ e[s] = __expf(v[s]-mx); sum += e[s]; }
  red[t]=sum; __syncthreads();
  for (int o=128;o>0;o>>=1){ if (t<o) red[t]+=red[t+o]; __syncthreads(); }
  sum = red[0];
  float inv = 1.0f/sum;
  unsigned short* Ar = A + ((size_t)z*NDIM + c)*NDIM;
  float* Mr = M + ((size_t)z*NDIM + c)*NDIM;
  #pragma unroll
  for (int s=0;s<4;s++){
    int b = t + s*256;
    float a = e[s]*inv;
    Ar[b] = f2bf(a);
    Mr[b] = 0.1f*a + ((b==c)?1.0f:0.0f);
  }
}

// A[z][c][b] -> AT[z][b][c], bf16 transpose
__global__ void k_transb(const unsigned short* __restrict__ A, unsigned short* __restrict__ AT){
  __shared__ unsigned short t[64][65];
  int z = blockIdx.z, bb = blockIdx.x, bc = blockIdx.y;
  int tx = threadIdx.x, ty = threadIdx.y; // (64,4)
  const unsigned short* Az = A + (size_t)z*NDIM*NDIM;
  #pragma unroll
  for (int r=0;r<16;r++){
    int c = bc*64 + ty + r*4;
    t[ty+r*4][tx] = Az[(size_t)c*NDIM + bb*64 + tx];
  }
  __syncthreads();
  unsigned short* Tz = AT + (size_t)z*NDIM*NDIM;
  #pragma unroll
  for (int r=0;r<16;r++){
    int b = bb*64 + ty + r*4;
    Tz[(size_t)b*NDIM + bc*64 + tx] = t[tx][ty+r*4];
  }
}

// ---------------- bf16 NT GEMM: C[M,N] = scale * A[M,K] * B[N,K]^T (+epilogues) ----------------
// Staging: global_load_lds w16, linear LDS [128][32] bf16, XOR-swizzled chunks
// (source pre-swizzle + swizzled ds_read; chunk ^= (row>>1)&3 balances ds_read_b128 phases).

struct GemmP {
  const unsigned short* A; const unsigned short* B;
  long long sA, sB;           // z-strides in elements
  int zShiftA, zShiftB;       // z index = z >> shift
  int lda, ldb;
  int K, tilesN;
  float* Cf; long long sC; int ldc; float beta;
  unsigned short* Cb; long long sCb; int ldcb;
  float* Madd;                // EPI3: += scale2 * acc ; EPI6: read-only
  const unsigned short* Sroot;// EPI4 addend root (uses sA/lda)
  const float* bias;          // EPI2 per-z bias
  float* outp;                // EPI4/5 output root
  float scale, scale2;
};

template<int EPI>
__global__ __launch_bounds__(256) void k_gemm(GemmP p){
  const int z = blockIdx.y;
  const int tm = blockIdx.x / p.tilesN;
  const int tn = blockIdx.x % p.tilesN;
  int jj=0, ii=0, kk=0;
  const unsigned short *Ap, *Bp;
  if (EPI==4 || EPI==5){
    jj = z>>3; ii = (z>>1)&3; kk = z&1;
    Ap = p.A + (size_t)(jj*2+kk)*(size_t)p.sA;
    Bp = p.B + (size_t)(ii*2+kk)*(size_t)p.sB;
  } else {
    Ap = p.A + (size_t)(z>>p.zShiftA)*(size_t)p.sA;
    Bp = p.B + (size_t)(z>>p.zShiftB)*(size_t)p.sB;
  }
  __shared__ unsigned short As[128*32];
  __shared__ unsigned short Bs[128*32];
  const int t = threadIdx.x;
  const int lane = t & 63;
  const int w = t >> 6;
  const int wm = w >> 1, wn = w & 1;

  f32x4 acc[4][4];
  #pragma unroll
  for (int m=0;m<4;m++)
    #pragma unroll
    for (int n=0;n<4;n++)
      acc[m][n] = (f32x4)(0.0f);

  // staging geometry: wave w, call c in {0,1}: row = w*32 + c*16 + (lane>>2),
  // source chunk = (lane&3) ^ ((row>>1)&3)  [involution; (row+16)>>1 has same &3]
  const int srow = w*32 + (lane>>2);
  const int swz  = ((lane&3) ^ ((srow>>1)&3)) * 8;
  const unsigned short* ga0 = Ap + (size_t)(tm*128 + srow)*p.lda + swz;
  const unsigned short* ga1 = Ap + (size_t)(tm*128 + srow + 16)*p.lda + swz;
  const unsigned short* gb0 = Bp + (size_t)(tn*128 + srow)*p.ldb + swz;
  const unsigned short* gb1 = Bp + (size_t)(tn*128 + srow + 16)*p.ldb + swz;
  unsigned short* lA0 = &As[w*1024];
  unsigned short* lA1 = &As[w*1024 + 512];
  unsigned short* lB0 = &Bs[w*1024];
  unsigned short* lB1 = &Bs[w*1024 + 512];

  const int rb = lane & 15, g = lane >> 4;
  const int rswz = (g ^ ((rb>>1)&3)) * 8;

  for (int k0=0; k0<p.K; k0+=32){
    __syncthreads();                    // prev compute done before overwrite
    gload16(ga0 + k0, lA0);
    gload16(ga1 + k0, lA1);
    gload16(gb0 + k0, lB0);
    gload16(gb1 + k0, lB1);
    __syncthreads();                    // compiler drains vmcnt before barrier
    bf16x8 af[4], bfr[4];
    #pragma unroll
    for (int m=0;m<4;m++) af[m]  = *(const bf16x8*)&As[(wm*64 + m*16 + rb)*32 + rswz];
    #pragma unroll
    for (int n=0;n<4;n++) bfr[n] = *(const bf16x8*)&Bs[(wn*64 + n*16 + rb)*32 + rswz];
    #pragma unroll
    for (int m=0;m<4;m++)
      #pragma unroll
      for (int n=0;n<4;n++)
        acc[m][n] = __builtin_amdgcn_mfma_f32_16x16x32_bf16(af[m], bfr[n], acc[m][n], 0, 0, 0);
  }

  const int rl = (lane>>4)*4;
  const int cl = lane & 15;
  const int row0 = tm*128 + wm*64;
  const int col0 = tn*128 + wn*64;
  #pragma unroll
  for (int m=0;m<4;m++){
    #pragma unroll
    for (int n=0;n<4;n++){
      #pragma unroll
      for (int r=0;r<4;r++){
        const int row = row0 + m*16 + rl + r;
        const int col = col0 + n*16 + cl;
        float v = acc[m][n][r];
        if (EPI==0){
          float* c = p.Cf + (size_t)z*p.sC + (size_t)row*p.ldc + col;
          float prev = (p.beta != 0.0f) ? *c : 0.0f;
          *c = p.scale*v + p.beta*prev;
        } else if (EPI==1){
          float* c = p.Cf + (size_t)z*p.sC + (size_t)row*p.ldc + col;
          float nv = p.scale*v + p.beta*(*c);
          *c = nv;
          p.Cb[(size_t)z*p.sCb + (size_t)row*p.ldcb + col] = f2bf(nv);
        } else if (EPI==2){
          float nv = p.scale*v + (p.bias ? p.bias[z] : 0.0f);
          p.Cb[(size_t)z*p.sCb + (size_t)row*p.ldcb + col] = f2bf(nv);
        } else if (EPI==3){
          p.Cb[(size_t)z*p.sCb + (size_t)row*p.ldcb + col] = f2bf(v);
          float* mp = p.Madd + (size_t)z*p.sC + (size_t)row*p.ldc + col;
          *mp += p.scale2 * v;
        } else if (EPI==4){
          float add = p.scale2 * bf2f(p.Sroot[(size_t)(jj*2+kk)*(size_t)p.sA + (size_t)row*p.lda + col]);
          size_t ob = (size_t)(jj*4+ii)*(2ull*NDIM*NDIM)*2 + (size_t)kk;
          p.outp[ob + ((size_t)row*NDIM + col)*2] = p.scale*v + add;
        } else if (EPI==5){
          size_t ob = (size_t)(jj*4+ii)*(2ull*NDIM*NDIM)*2 + (size_t)kk;
          p.outp[ob + ((size_t)((size_t)NDIM*NDIM + (size_t)row*NDIM + col))*2] = p.scale*v;
        } else if (EPI==6){
          // Aan_bf16 = bf16(0.9 * (M + scale2 * P_last)) ; no M write-back, no P store
          float mval = p.Madd[(size_t)z*p.sC + (size_t)row*p.ldc + col];
          p.Cb[(size_t)z*p.sCb + (size_t)row*p.ldcb + col] = f2bf(0.9f*(mval + p.scale2*v));
        }
      }
    }
  }
}

// ---------------- host ----------------

extern "C" void kernel_launch(void* const* d_in, const int* in_sizes, int n_in,
                              void* d_out, int out_size, void* d_ws, size_t ws_size,
                              hipStream_t stream){
  (void)in_sizes; (void)n_in; (void)out_size; (void)ws_size;
  const float* x  = (const float*)d_in[0];
  const float* Wb = (const float*)d_in[1];
  const float* We = (const float*)d_in[2];
  const float* be = (const float*)d_in[3];
  float* out = (float*)d_out;
  char* ws = (char*)d_ws;

  // arena (overlaid by liveness):
  unsigned short* Abuf  = (unsigned short*)(ws + 0);        // 16 MB (after feats phase)
  unsigned short* xhi   = (unsigned short*)(ws + 0);        // 2 MB
  unsigned short* xlo   = (unsigned short*)(ws + 2*MB);     // 2 MB
  unsigned short* wbth  = (unsigned short*)(ws + 4*MB);     // 4 MB
  unsigned short* wbtl  = (unsigned short*)(ws + 8*MB);     // 4 MB
  float*          featf = (float*)(ws + 12*MB);             // 8 MB
  unsigned short* Pa    = (unsigned short*)(ws + 20*MB);    // 16 MB (after S phase)
  unsigned short* featb = (unsigned short*)(ws + 20*MB);    // 4 MB
  unsigned short* WT    = (unsigned short*)(ws + 24*MB);    // 4 MB
  unsigned short* Tb    = (unsigned short*)(ws + 28*MB);    // 8 MB
  unsigned short* Sb    = (unsigned short*)(ws + 36*MB);    // 16 MB
  unsigned short* ATb   = (unsigned short*)(ws + 52*MB);    // 16 MB
  float*          Mf    = (float*)(ws + 68*MB);             // 32 MB
  unsigned short* Pb    = (unsigned short*)(ws + 100*MB);   // 16 MB

  // 1. splits / transposes of weights
  k_split_x<<<dim3(1024), dim3(256), 0, stream>>>(x, xhi, xlo);
  k_trans_split<<<dim3(64,32), dim3(32,8), 0, stream>>>(Wb, wbth, wbtl);
  k_wt<<<dim3(16,16,8), dim3(32,8), 0, stream>>>(We, WT);

  // 2. feats = x @ Wb  (split: hi*hi + hi*lo + lo*hi), M=1024 N=2048 K=1024
  auto feats_launch = [&](const unsigned short* Aop, const unsigned short* Bop, float beta, bool last){
    GemmP q{};
    q.A = Aop; q.B = Bop; q.sA = 0; q.sB = 0; q.zShiftA = 0; q.zShiftB = 0;
    q.lda = 1024; q.ldb = 1024; q.K = 1024; q.tilesN = 16;
    q.Cf = featf; q.sC = 0; q.ldc = 2048; q.beta = beta;
    q.Cb = featb; q.sCb = 0; q.ldcb = 2048;
    q.scale = 1.0f; q.scale2 = 0.0f;
    if (last) k_gemm<1><<<dim3(8*16,1), dim3(256), 0, stream>>>(q);
    else      k_gemm<0><<<dim3(8*16,1), dim3(256), 0, stream>>>(q);
  };
  feats_launch(xhi, wbth, 0.0f, false);
  feats_launch(xhi, wbtl, 1.0f, false);
  feats_launch(xlo, wbth, 1.0f, true);

  // 3. T[z] = xb_j @ WT_z^T   (z=j*2+k), M=1024 N=512 K=512
  {
    GemmP q{};
    q.A = featb; q.sA = 512; q.zShiftA = 1; q.lda = 2048;
    q.B = WT;    q.sB = (long long)512*512; q.zShiftB = 0; q.ldb = 512;
    q.K = 512; q.tilesN = 4;
    q.Cb = Tb; q.sCb = (long long)1024*512; q.ldcb = 512;
    q.bias = nullptr; q.scale = 1.0f;
    k_gemm<2><<<dim3(8*4,8), dim3(256), 0, stream>>>(q);
  }

  // 4. S[z] = T[z] @ xb_j^T + b_embed[z], M=1024 N=1024 K=512
  {
    GemmP q{};
    q.A = Tb;    q.sA = (long long)1024*512; q.zShiftA = 0; q.lda = 512;
    q.B = featb; q.sB = 512; q.zShiftB = 1; q.ldb = 2048;
    q.K = 512; q.tilesN = 8;
    q.Cb = Sb; q.sCb = (long long)NDIM*NDIM; q.ldcb = 1024;
    q.bias = be; q.scale = 1.0f;
    k_gemm<2><<<dim3(8*8,8), dim3(256), 0, stream>>>(q);
  }

  // 5. softmax -> A, M = I + alpha*A ; then AT
  k_softmax<<<dim3(1024,8), dim3(256), 0, stream>>>(Sb, Abuf, Mf);
  k_transb<<<dim3(16,16,8), dim3(64,4), 0, stream>>>(Abuf, ATb);

  // 6. Neumann: P_t = P_{t-1} @ A  (NT with AT), M += alpha^t * P_t, t=2..5;
  //    t=6 fused: Aan = bf16(0.9*(M + alpha^6 * P_6)) via EPI6 (no M/P write-back)
  auto neumann = [&](const unsigned short* Aop, unsigned short* dst, float a_t, bool last){
    GemmP q{};
    q.A = Aop; q.sA = (long long)NDIM*NDIM; q.zShiftA = 0; q.lda = 1024;
    q.B = ATb; q.sB = (long long)NDIM*NDIM; q.zShiftB = 0; q.ldb = 1024;
    q.K = 1024; q.tilesN = 8;
    q.Cb = dst; q.sCb = (long long)NDIM*NDIM; q.ldcb = 1024;
    q.Madd = Mf; q.sC = (long long)NDIM*NDIM; q.ldc = 1024;
    q.scale = 1.0f; q.scale2 = a_t;
    if (last) k_gemm<6><<<dim3(8*8,8), dim3(256), 0, stream>>>(q);
    else      k_gemm<3><<<dim3(8*8,8), dim3(256), 0, stream>>>(q);
  };
  neumann(Abuf, Pa, 1e-2f, false);
  neumann(Pa,   Pb, 1e-3f, false);
  neumann(Pb,   Pa, 1e-4f, false);
  neumann(Pa,   Pb, 1e-5f, false);
  neumann(Pb,   Pa, 1e-6f, true);   // Pa <- Aan_bf16

  // 7. one[j,i,a,c,k] = 0.1 * (S_jk @ A_ik^T)[a,c] + 0.9 * S_jk[a,c]
  {
    GemmP q{};
    q.A = Sb;   q.sA = (long long)NDIM*NDIM; q.lda = 1024;
    q.B = Abuf; q.sB = (long long)NDIM*NDIM; q.ldb = 1024;
    q.K = 1024; q.tilesN = 8;
    q.Sroot = Sb; q.outp = out;
    q.scale = 0.1f; q.scale2 = 0.9f;
    k_gemm<4><<<dim3(8*8,32), dim3(256), 0, stream>>>(q);
  }
  // 8. ana[j,i,a,c,k] = (S_jk @ Aan_ik^T)[a,c]   (0.9 already folded into Aan)
  {
    GemmP q{};
    q.A = Sb; q.sA = (long long)NDIM*NDIM; q.lda = 1024;
    q.B = Pa; q.sB = (long long)NDIM*NDIM; q.ldb = 1024;
    q.K = 1024; q.tilesN = 8;
    q.outp = out;
    q.scale = 1.0f; q.scale2 = 0.0f;
    k_gemm<5><<<dim3(8*8,32), dim3(256), 0, stream>>>(q);
  }
}

// Round 5
// 697.348 us; speedup vs baseline: 1.3149x; 1.2531x over previous
//
#include <hip/hip_runtime.h>

#define NDIM 1024
#define MB (1ull<<20)

using f32x4  = __attribute__((ext_vector_type(4))) float;
using bf16x8 = __attribute__((ext_vector_type(8))) __bf16;
using u16x8  = __attribute__((ext_vector_type(8))) unsigned short;

__device__ __forceinline__ float bf2f(unsigned short u){
  union{unsigned int i; float f;} x; x.i = ((unsigned int)u)<<16; return x.f;
}
__device__ __forceinline__ unsigned short f2bf(float f){
  union{float fl; unsigned int i;} u; u.fl = f;
  unsigned int x = u.i;
  return (unsigned short)((x + 0x7fffu + ((x>>16)&1u)) >> 16);
}

// async global->LDS, 16B per lane. Dest must be wave-uniform base; HW adds lane*16.
__device__ __forceinline__ void gload16(const unsigned short* g, unsigned short* l){
  __builtin_amdgcn_global_load_lds(
      (const __attribute__((address_space(1))) void*)g,
      (__attribute__((address_space(3))) void*)l,
      16, 0, 0);
}

// ---------------- small kernels ----------------

// x (f32) -> hi/lo bf16 split
__global__ void k_split_x(const float* __restrict__ x, unsigned short* __restrict__ hi,
                          unsigned short* __restrict__ lo){
  size_t idx = ((size_t)blockIdx.x*256 + threadIdx.x)*4;
  float4 v = *(const float4*)(x+idx);
  float vv[4] = {v.x, v.y, v.z, v.w};
  ushort4 h, l;
  unsigned short* hp = (unsigned short*)&h;
  unsigned short* lp = (unsigned short*)&l;
  #pragma unroll
  for (int s=0;s<4;s++){
    unsigned short hb = f2bf(vv[s]);
    hp[s] = hb;
    lp[s] = f2bf(vv[s] - bf2f(hb));
  }
  *(ushort4*)(hi+idx) = h;
  *(ushort4*)(lo+idx) = l;
}

// Wb [1024(c)][2048(d)] f32 -> WbT [2048(d)][1024(c)] hi/lo bf16
__global__ void k_trans_split(const float* __restrict__ Wb, unsigned short* __restrict__ hi,
                              unsigned short* __restrict__ lo){
  __shared__ float t[32][33];
  int bd = blockIdx.x, bc = blockIdx.y;
  int tx = threadIdx.x, ty = threadIdx.y;
  #pragma unroll
  for (int r=0;r<4;r++){
    int c = bc*32 + ty + r*8;
    t[ty+r*8][tx] = Wb[(size_t)c*2048 + bd*32 + tx];
  }
  __syncthreads();
  #pragma unroll
  for (int r=0;r<4;r++){
    int d = bd*32 + ty + r*8, c = bc*32 + tx;
    float v = t[tx][ty+r*8];
    unsigned short h = f2bf(v);
    hi[(size_t)d*1024 + c] = h;
    lo[(size_t)d*1024 + c] = f2bf(v - bf2f(h));
  }
}

// W_embed [j][c][d][k] f32 -> WT [z=j*2+k][d][c] bf16
__global__ void k_wt(const float* __restrict__ W, unsigned short* __restrict__ WT){
  __shared__ float t[32][33];
  int z = blockIdx.z; int j = z>>1, k = z&1;
  int bd = blockIdx.x, bc = blockIdx.y;
  int tx = threadIdx.x, ty = threadIdx.y;
  #pragma unroll
  for (int r=0;r<4;r++){
    int c = bc*32 + ty + r*8, d = bd*32 + tx;
    t[ty+r*8][tx] = W[(((size_t)j*512 + c)*512 + d)*2 + k];
  }
  __syncthreads();
  #pragma unroll
  for (int r=0;r<4;r++){
    int d = bd*32 + ty + r*8, c = bc*32 + tx;
    WT[((size_t)z*512 + d)*512 + c] = f2bf(t[tx][ty+r*8]);
  }
}

// row softmax with diag mask: S_bf16[z][c][b] -> A bf16
__global__ void k_softmax(const unsigned short* __restrict__ S, unsigned short* __restrict__ A){
  int z = blockIdx.y, c = blockIdx.x, t = threadIdx.x;
  const unsigned short* row = S + ((size_t)z*NDIM + c)*NDIM;
  __shared__ float red[256];
  float v[4];
  float mx = -1e30f;
  #pragma unroll
  for (int s=0;s<4;s++){
    int b = t + s*256;
    float x = bf2f(row[b]);
    if (b==c) x = -1e30f;
    v[s] = x; mx = fmaxf(mx, x);
  }
  red[t]=mx; __syncthreads();
  for (int o=128;o>0;o>>=1){ if (t<o) red[t]=fmaxf(red[t],red[t+o]); __syncthreads(); }
  mx = red[0]; __syncthreads();
  float e[4]; float sum=0.f;
  #pragma unroll
  for (int s=0;s<4;s++){ e[s] = __expf(v[s]-mx); sum += e[s]; }
  red[t]=sum; __syncthreads();
  for (int o=128;o>0;o>>=1){ if (t<o) red[t]+=red[t+o]; __syncthreads(); }
  sum = red[0];
  float inv = 1.0f/sum;
  unsigned short* Ar = A + ((size_t)z*NDIM + c)*NDIM;
  #pragma unroll
  for (int s=0;s<4;s++){
    int b = t + s*256;
    Ar[b] = f2bf(e[s]*inv);
  }
}

// A[z][c][b] -> AT[z][b][c], bf16 transpose
__global__ void k_transb(const unsigned short* __restrict__ A, unsigned short* __restrict__ AT){
  __shared__ unsigned short t[64][65];
  int z = blockIdx.z, bb = blockIdx.x, bc = blockIdx.y;
  int tx = threadIdx.x, ty = threadIdx.y; // (64,4)
  const unsigned short* Az = A + (size_t)z*NDIM*NDIM;
  #pragma unroll
  for (int r=0;r<16;r++){
    int c = bc*64 + ty + r*4;
    t[ty+r*4][tx] = Az[(size_t)c*NDIM + bb*64 + tx];
  }
  __syncthreads();
  unsigned short* Tz = AT + (size_t)z*NDIM*NDIM;
  #pragma unroll
  for (int r=0;r<16;r++){
    int b = bb*64 + ty + r*4;
    Tz[(size_t)b*NDIM + bc*64 + tx] = t[tx][ty+r*4];
  }
}

// Aan = bf16(0.9*(I + 0.1*A + 0.01*A2 + 0.001*A3))
__global__ void k_combine(const unsigned short* __restrict__ A, const unsigned short* __restrict__ A2,
                          const unsigned short* __restrict__ A3, unsigned short* __restrict__ Aan){
  size_t idx = ((size_t)blockIdx.x*256 + threadIdx.x)*8;
  int cb = (int)(idx & ((size_t)NDIM*NDIM - 1));
  int c = cb >> 10, b0 = cb & 1023;
  u16x8 a  = *(const u16x8*)(A+idx);
  u16x8 a2 = *(const u16x8*)(A2+idx);
  u16x8 a3 = *(const u16x8*)(A3+idx);
  u16x8 o;
  #pragma unroll
  for (int s=0;s<8;s++){
    float v = 0.1f*bf2f(a[s]) + 0.01f*bf2f(a2[s]) + 0.001f*bf2f(a3[s]);
    if (b0+s == c) v += 1.0f;
    o[s] = f2bf(0.9f*v);
  }
  *(u16x8*)(Aan+idx) = o;
}

// ---------------- bf16 NT GEMM: C[M,N] = scale * Sum_s A_s[M,K] * B_s[N,K]^T (+epilogues) ----------
// Staging: global_load_lds w16, linear LDS [128][32] bf16, XOR-swizzled chunks
// (source pre-swizzle + swizzled ds_read; chunk ^= (row>>1)&3 balances ds_read_b128 phases).

struct GemmP {
  const unsigned short* Aseg[3]; const unsigned short* Bseg[3];
  long long sA, sB;           // z-strides in elements
  int zShiftA, zShiftB;       // z index = z >> shift
  int lda, ldb;
  int K, tilesN;              // K per segment
  unsigned short* Cb; long long sCb; int ldcb;
  const unsigned short* Sroot;// EPI4 addend root (uses sA/lda)
  const float* bias;          // EPI2 per-z bias
  float* outp;                // EPI4/5 output root
  float scale, scale2;
};

template<int EPI, int NSEG>
__global__ __launch_bounds__(256) void k_gemm(GemmP p){
  const int z = blockIdx.y;
  const int tm = blockIdx.x / p.tilesN;
  const int tn = blockIdx.x % p.tilesN;
  int jj=0, ii=0, kk=0;
  size_t zoffA, zoffB;
  if (EPI==4 || EPI==5){
    jj = z>>3; ii = (z>>1)&3; kk = z&1;
    zoffA = (size_t)(jj*2+kk)*(size_t)p.sA;
    zoffB = (size_t)(ii*2+kk)*(size_t)p.sB;
  } else {
    zoffA = (size_t)(z>>p.zShiftA)*(size_t)p.sA;
    zoffB = (size_t)(z>>p.zShiftB)*(size_t)p.sB;
  }
  __shared__ unsigned short As[128*32];
  __shared__ unsigned short Bs[128*32];
  const int t = threadIdx.x;
  const int lane = t & 63;
  const int w = t >> 6;
  const int wm = w >> 1, wn = w & 1;

  f32x4 acc[4][4];
  #pragma unroll
  for (int m=0;m<4;m++)
    #pragma unroll
    for (int n=0;n<4;n++)
      acc[m][n] = (f32x4)(0.0f);

  // staging geometry: wave w, call c in {0,1}: row = w*32 + c*16 + (lane>>2),
  // source chunk = (lane&3) ^ ((row>>1)&3)  [involution; (row+16)>>1 has same &3]
  const int srow = w*32 + (lane>>2);
  const int swz  = ((lane&3) ^ ((srow>>1)&3)) * 8;
  const size_t aoff0 = (size_t)(tm*128 + srow)*p.lda + swz;
  const size_t aoff1 = (size_t)(tm*128 + srow + 16)*p.lda + swz;
  const size_t boff0 = (size_t)(tn*128 + srow)*p.ldb + swz;
  const size_t boff1 = (size_t)(tn*128 + srow + 16)*p.ldb + swz;
  unsigned short* lA0 = &As[w*1024];
  unsigned short* lA1 = &As[w*1024 + 512];
  unsigned short* lB0 = &Bs[w*1024];
  unsigned short* lB1 = &Bs[w*1024 + 512];

  const int rb = lane & 15, g = lane >> 4;
  const int rswz = (g ^ ((rb>>1)&3)) * 8;

  #pragma unroll
  for (int s=0;s<NSEG;s++){
    const unsigned short* ga = p.Aseg[s] + zoffA;
    const unsigned short* gb = p.Bseg[s] + zoffB;
    for (int k0=0; k0<p.K; k0+=32){
      __syncthreads();                    // prev compute done before overwrite
      gload16(ga + aoff0 + k0, lA0);
      gload16(ga + aoff1 + k0, lA1);
      gload16(gb + boff0 + k0, lB0);
      gload16(gb + boff1 + k0, lB1);
      __syncthreads();                    // compiler drains vmcnt before barrier
      bf16x8 af[4], bfr[4];
      #pragma unroll
      for (int m=0;m<4;m++) af[m]  = *(const bf16x8*)&As[(wm*64 + m*16 + rb)*32 + rswz];
      #pragma unroll
      for (int n=0;n<4;n++) bfr[n] = *(const bf16x8*)&Bs[(wn*64 + n*16 + rb)*32 + rswz];
      #pragma unroll
      for (int m=0;m<4;m++)
        #pragma unroll
        for (int n=0;n<4;n++)
          acc[m][n] = __builtin_amdgcn_mfma_f32_16x16x32_bf16(af[m], bfr[n], acc[m][n], 0, 0, 0);
    }
  }

  const int rl = (lane>>4)*4;
  const int cl = lane & 15;
  const int row0 = tm*128 + wm*64;
  const int col0 = tn*128 + wn*64;
  #pragma unroll
  for (int m=0;m<4;m++){
    #pragma unroll
    for (int n=0;n<4;n++){
      #pragma unroll
      for (int r=0;r<4;r++){
        const int row = row0 + m*16 + rl + r;
        const int col = col0 + n*16 + cl;
        float v = acc[m][n][r];
        if (EPI==2){
          float nv = p.scale*v + (p.bias ? p.bias[z] : 0.0f);
          p.Cb[(size_t)z*p.sCb + (size_t)row*p.ldcb + col] = f2bf(nv);
        } else if (EPI==4){
          float add = p.scale2 * bf2f(p.Sroot[(size_t)(jj*2+kk)*(size_t)p.sA + (size_t)row*p.lda + col]);
          size_t ob = (size_t)(jj*4+ii)*(2ull*NDIM*NDIM)*2 + (size_t)kk;
          p.outp[ob + ((size_t)row*NDIM + col)*2] = p.scale*v + add;
        } else if (EPI==5){
          size_t ob = (size_t)(jj*4+ii)*(2ull*NDIM*NDIM)*2 + (size_t)kk;
          p.outp[ob + ((size_t)((size_t)NDIM*NDIM + (size_t)row*NDIM + col))*2] = p.scale*v;
        }
      }
    }
  }
}

// ---------------- host ----------------

extern "C" void kernel_launch(void* const* d_in, const int* in_sizes, int n_in,
                              void* d_out, int out_size, void* d_ws, size_t ws_size,
                              hipStream_t stream){
  (void)in_sizes; (void)n_in; (void)out_size; (void)ws_size;
  const float* x  = (const float*)d_in[0];
  const float* Wb = (const float*)d_in[1];
  const float* We = (const float*)d_in[2];
  const float* be = (const float*)d_in[3];
  float* out = (float*)d_out;
  char* ws = (char*)d_ws;

  // arena (ws_size ~1 GB; no overlays needed)
  unsigned short* xhi   = (unsigned short*)(ws + 0);        // 2 MB
  unsigned short* xlo   = (unsigned short*)(ws + 2*MB);     // 2 MB
  unsigned short* wbth  = (unsigned short*)(ws + 4*MB);     // 4 MB
  unsigned short* wbtl  = (unsigned short*)(ws + 8*MB);     // 4 MB
  unsigned short* featb = (unsigned short*)(ws + 12*MB);    // 4 MB
  unsigned short* WT    = (unsigned short*)(ws + 16*MB);    // 4 MB
  unsigned short* Tb    = (unsigned short*)(ws + 20*MB);    // 8 MB
  unsigned short* Sb    = (unsigned short*)(ws + 28*MB);    // 16 MB
  unsigned short* Abuf  = (unsigned short*)(ws + 44*MB);    // 16 MB
  unsigned short* ATb   = (unsigned short*)(ws + 60*MB);    // 16 MB
  unsigned short* A2b   = (unsigned short*)(ws + 76*MB);    // 16 MB
  unsigned short* A3b   = (unsigned short*)(ws + 92*MB);    // 16 MB
  unsigned short* Aan   = (unsigned short*)(ws + 108*MB);   // 16 MB

  // 1. splits / transposes of weights
  k_split_x<<<dim3(1024), dim3(256), 0, stream>>>(x, xhi, xlo);
  k_trans_split<<<dim3(64,32), dim3(32,8), 0, stream>>>(Wb, wbth, wbtl);
  k_wt<<<dim3(16,16,8), dim3(32,8), 0, stream>>>(We, WT);

  // 2. feats = x @ Wb, fused hi/lo split via 3 K-segments: xhi*Wth + xhi*Wtl + xlo*Wth
  {
    GemmP q{};
    q.Aseg[0]=xhi; q.Bseg[0]=wbth;
    q.Aseg[1]=xhi; q.Bseg[1]=wbtl;
    q.Aseg[2]=xlo; q.Bseg[2]=wbth;
    q.sA = 0; q.sB = 0; q.zShiftA = 0; q.zShiftB = 0;
    q.lda = 1024; q.ldb = 1024; q.K = 1024; q.tilesN = 16;
    q.Cb = featb; q.sCb = 0; q.ldcb = 2048;
    q.bias = nullptr; q.scale = 1.0f;
    k_gemm<2,3><<<dim3(8*16,1), dim3(256), 0, stream>>>(q);
  }

  // 3. T[z] = xb_j @ WT_z^T   (z=j*2+k), M=1024 N=512 K=512
  {
    GemmP q{};
    q.Aseg[0] = featb; q.sA = 512; q.zShiftA = 1; q.lda = 2048;
    q.Bseg[0] = WT;    q.sB = (long long)512*512; q.zShiftB = 0; q.ldb = 512;
    q.K = 512; q.tilesN = 4;
    q.Cb = Tb; q.sCb = (long long)1024*512; q.ldcb = 512;
    q.bias = nullptr; q.scale = 1.0f;
    k_gemm<2,1><<<dim3(8*4,8), dim3(256), 0, stream>>>(q);
  }

  // 4. S[z] = T[z] @ xb_j^T + b_embed[z], M=1024 N=1024 K=512
  {
    GemmP q{};
    q.Aseg[0] = Tb;    q.sA = (long long)1024*512; q.zShiftA = 0; q.lda = 512;
    q.Bseg[0] = featb; q.sB = 512; q.zShiftB = 1; q.ldb = 2048;
    q.K = 512; q.tilesN = 8;
    q.Cb = Sb; q.sCb = (long long)NDIM*NDIM; q.ldcb = 1024;
    q.bias = be; q.scale = 1.0f;
    k_gemm<2,1><<<dim3(8*8,8), dim3(256), 0, stream>>>(q);
  }

  // 5. softmax -> A ; AT = A^T
  k_softmax<<<dim3(1024,8), dim3(256), 0, stream>>>(Sb, Abuf);
  k_transb<<<dim3(16,16,8), dim3(64,4), 0, stream>>>(Abuf, ATb);

  // 6. Neumann (truncated at t=3): A2 = A@A, A3 = A2@A   (NT with B=ATb)
  auto pgemm = [&](const unsigned short* Aop, unsigned short* dst){
    GemmP q{};
    q.Aseg[0] = Aop; q.sA = (long long)NDIM*NDIM; q.zShiftA = 0; q.lda = 1024;
    q.Bseg[0] = ATb; q.sB = (long long)NDIM*NDIM; q.zShiftB = 0; q.ldb = 1024;
    q.K = 1024; q.tilesN = 8;
    q.Cb = dst; q.sCb = (long long)NDIM*NDIM; q.ldcb = 1024;
    q.bias = nullptr; q.scale = 1.0f;
    k_gemm<2,1><<<dim3(8*8,8), dim3(256), 0, stream>>>(q);
  };
  pgemm(Abuf, A2b);
  pgemm(A2b,  A3b);

  // 7. Aan = bf16(0.9*(I + 0.1A + 0.01A2 + 0.001A3))
  k_combine<<<dim3(4096), dim3(256), 0, stream>>>(Abuf, A2b, A3b, Aan);

  // 8. one[j,i,a,c,k] = 0.1 * (S_jk @ A_ik^T)[a,c] + 0.9 * S_jk[a,c]
  {
    GemmP q{};
    q.Aseg[0] = Sb;   q.sA = (long long)NDIM*NDIM; q.lda = 1024;
    q.Bseg[0] = Abuf; q.sB = (long long)NDIM*NDIM; q.ldb = 1024;
    q.K = 1024; q.tilesN = 8;
    q.Sroot = Sb; q.outp = out;
    q.scale = 0.1f; q.scale2 = 0.9f;
    k_gemm<4,1><<<dim3(8*8,32), dim3(256), 0, stream>>>(q);
  }
  // 9. ana[j,i,a,c,k] = (S_jk @ Aan_ik^T)[a,c]   (0.9, I, and powers folded into Aan)
  {
    GemmP q{};
    q.Aseg[0] = Sb;  q.sA = (long long)NDIM*NDIM; q.lda = 1024;
    q.Bseg[0] = Aan; q.sB = (long long)NDIM*NDIM; q.ldb = 1024;
    q.K = 1024; q.tilesN = 8;
    q.outp = out;
    q.scale = 1.0f; q.scale2 = 0.0f;
    k_gemm<5,1><<<dim3(8*8,32), dim3(256), 0, stream>>>(q);
  }
}

// Round 6
// 659.334 us; speedup vs baseline: 1.3907x; 1.0577x over previous
//
#include <hip/hip_runtime.h>

#define NDIM 1024
#define NN (1024ull*1024ull)
#define MB (1ull<<20)

using f32x4  = __attribute__((ext_vector_type(4))) float;
using bf16x8 = __attribute__((ext_vector_type(8))) __bf16;
using u16x8  = __attribute__((ext_vector_type(8))) unsigned short;

__device__ __forceinline__ float bf2f(unsigned short u){
  union{unsigned int i; float f;} x; x.i = ((unsigned int)u)<<16; return x.f;
}
__device__ __forceinline__ unsigned short f2bf(float f){
  union{float fl; unsigned int i;} u; u.fl = f;
  unsigned int x = u.i;
  return (unsigned short)((x + 0x7fffu + ((x>>16)&1u)) >> 16);
}

// async global->LDS, 16B per lane. Dest must be wave-uniform base; HW adds lane*16.
__device__ __forceinline__ void gload16(const unsigned short* g, unsigned short* l){
  __builtin_amdgcn_global_load_lds(
      (const __attribute__((address_space(1))) void*)g,
      (__attribute__((address_space(3))) void*)l,
      16, 0, 0);
}

// ---------------- small kernels ----------------

__global__ void k_split_x(const float* __restrict__ x, unsigned short* __restrict__ hi,
                          unsigned short* __restrict__ lo){
  size_t idx = ((size_t)blockIdx.x*256 + threadIdx.x)*4;
  float4 v = *(const float4*)(x+idx);
  float vv[4] = {v.x, v.y, v.z, v.w};
  ushort4 h, l;
  unsigned short* hp = (unsigned short*)&h;
  unsigned short* lp = (unsigned short*)&l;
  #pragma unroll
  for (int s=0;s<4;s++){
    unsigned short hb = f2bf(vv[s]);
    hp[s] = hb;
    lp[s] = f2bf(vv[s] - bf2f(hb));
  }
  *(ushort4*)(hi+idx) = h;
  *(ushort4*)(lo+idx) = l;
}

__global__ void k_trans_split(const float* __restrict__ Wb, unsigned short* __restrict__ hi,
                              unsigned short* __restrict__ lo){
  __shared__ float t[32][33];
  int bd = blockIdx.x, bc = blockIdx.y;
  int tx = threadIdx.x, ty = threadIdx.y;
  #pragma unroll
  for (int r=0;r<4;r++){
    int c = bc*32 + ty + r*8;
    t[ty+r*8][tx] = Wb[(size_t)c*2048 + bd*32 + tx];
  }
  __syncthreads();
  #pragma unroll
  for (int r=0;r<4;r++){
    int d = bd*32 + ty + r*8, c = bc*32 + tx;
    float v = t[tx][ty+r*8];
    unsigned short h = f2bf(v);
    hi[(size_t)d*1024 + c] = h;
    lo[(size_t)d*1024 + c] = f2bf(v - bf2f(h));
  }
}

__global__ void k_wt(const float* __restrict__ W, unsigned short* __restrict__ WT){
  __shared__ float t[32][33];
  int z = blockIdx.z; int j = z>>1, k = z&1;
  int bd = blockIdx.x, bc = blockIdx.y;
  int tx = threadIdx.x, ty = threadIdx.y;
  #pragma unroll
  for (int r=0;r<4;r++){
    int c = bc*32 + ty + r*8, d = bd*32 + tx;
    t[ty+r*8][tx] = W[(((size_t)j*512 + c)*512 + d)*2 + k];
  }
  __syncthreads();
  #pragma unroll
  for (int r=0;r<4;r++){
    int d = bd*32 + ty + r*8, c = bc*32 + tx;
    WT[((size_t)z*512 + d)*512 + c] = f2bf(t[tx][ty+r*8]);
  }
}

__global__ void k_softmax(const unsigned short* __restrict__ S, unsigned short* __restrict__ A){
  int z = blockIdx.y, c = blockIdx.x, t = threadIdx.x;
  const unsigned short* row = S + ((size_t)z*NDIM + c)*NDIM;
  __shared__ float red[256];
  float v[4];
  float mx = -1e30f;
  #pragma unroll
  for (int s=0;s<4;s++){
    int b = t + s*256;
    float x = bf2f(row[b]);
    if (b==c) x = -1e30f;
    v[s] = x; mx = fmaxf(mx, x);
  }
  red[t]=mx; __syncthreads();
  for (int o=128;o>0;o>>=1){ if (t<o) red[t]=fmaxf(red[t],red[t+o]); __syncthreads(); }
  mx = red[0]; __syncthreads();
  float e[4]; float sum=0.f;
  #pragma unroll
  for (int s=0;s<4;s++){ e[s] = __expf(v[s]-mx); sum += e[s]; }
  red[t]=sum; __syncthreads();
  for (int o=128;o>0;o>>=1){ if (t<o) red[t]+=red[t+o]; __syncthreads(); }
  sum = red[0];
  float inv = 1.0f/sum;
  unsigned short* Ar = A + ((size_t)z*NDIM + c)*NDIM;
  #pragma unroll
  for (int s=0;s<4;s++){
    int b = t + s*256;
    Ar[b] = f2bf(e[s]*inv);
  }
}

__global__ void k_transb(const unsigned short* __restrict__ A, unsigned short* __restrict__ AT){
  __shared__ unsigned short t[64][65];
  int z = blockIdx.z, bb = blockIdx.x, bc = blockIdx.y;
  int tx = threadIdx.x, ty = threadIdx.y; // (64,4)
  const unsigned short* Az = A + (size_t)z*NN;
  #pragma unroll
  for (int r=0;r<16;r++){
    int c = bc*64 + ty + r*4;
    t[ty+r*4][tx] = Az[(size_t)c*NDIM + bb*64 + tx];
  }
  __syncthreads();
  unsigned short* Tz = AT + (size_t)z*NN;
  #pragma unroll
  for (int r=0;r<16;r++){
    int b = bb*64 + ty + r*4;
    Tz[(size_t)b*NDIM + bc*64 + tx] = t[tx][ty+r*4];
  }
}

// Aan = bf16(0.9*(I + 0.1*A + 0.01*A2 + 0.001*A3))
__global__ void k_combine(const unsigned short* __restrict__ A, const unsigned short* __restrict__ A2,
                          const unsigned short* __restrict__ A3, unsigned short* __restrict__ Aan){
  size_t idx = ((size_t)blockIdx.x*256 + threadIdx.x)*8;
  int cb = (int)(idx & (NN - 1));
  int c = cb >> 10, b0 = cb & 1023;
  u16x8 a  = *(const u16x8*)(A+idx);
  u16x8 a2 = *(const u16x8*)(A2+idx);
  u16x8 a3 = *(const u16x8*)(A3+idx);
  u16x8 o;
  #pragma unroll
  for (int s=0;s<8;s++){
    float v = 0.1f*bf2f(a[s]) + 0.01f*bf2f(a2[s]) + 0.001f*bf2f(a3[s]);
    if (b0+s == c) v += 1.0f;
    o[s] = f2bf(0.9f*v);
  }
  *(u16x8*)(Aan+idx) = o;
}

// ---------------- 2-phase double-buffered bf16 NT GEMM core helpers ----------------
// Staging: global_load_lds w16, linear LDS [128][32] bf16 per buffer, XOR-swizzled chunks
// (source pre-swizzle + swizzled ds_read; chunk ^= (row>>1)&3).
// Pipeline (T3 minimum 2-phase): prologue STAGE(buf0); sync; loop { STAGE(buf^1, t+1);
// compute buf; sync; flip }. End-of-iter barrier guarantees buf^1 was fully read one
// iteration earlier (safe overwrite) and drains the prefetch vmcnt (ready next iter).

struct GemmP {
  const unsigned short* Aseg[3]; const unsigned short* Bseg[3];
  long long sA, sB;           // z-strides in elements
  int zShiftA, zShiftB;       // z index = z >> shift
  int lda, ldb;
  int K, tilesN;              // K per segment
  unsigned short* Cb; long long sCb; int ldcb;
  const float* bias;          // per-z bias
  float scale;
};

// generic: C_bf16 = scale * Sum_s A_s B_s^T + bias
template<int NSEG>
__global__ __launch_bounds__(256) void k_gemm(GemmP p){
  const int z = blockIdx.y;
  const int tm = blockIdx.x / p.tilesN;
  const int tn = blockIdx.x % p.tilesN;
  const size_t zoffA = (size_t)(z>>p.zShiftA)*(size_t)p.sA;
  const size_t zoffB = (size_t)(z>>p.zShiftB)*(size_t)p.sB;
  __shared__ unsigned short As[2][4096];
  __shared__ unsigned short Bs[2][4096];
  const int t = threadIdx.x;
  const int lane = t & 63;
  const int w = t >> 6;
  const int wm = w >> 1, wn = w & 1;

  f32x4 acc[4][4];
  #pragma unroll
  for (int m=0;m<4;m++)
    #pragma unroll
    for (int n=0;n<4;n++)
      acc[m][n] = (f32x4)(0.0f);

  const int srow = w*32 + (lane>>2);
  const int swz  = ((lane&3) ^ ((srow>>1)&3)) * 8;
  const size_t aoff0 = (size_t)(tm*128 + srow)*p.lda + swz;
  const size_t aoff1 = (size_t)(tm*128 + srow + 16)*p.lda + swz;
  const size_t boff0 = (size_t)(tn*128 + srow)*p.ldb + swz;
  const size_t boff1 = (size_t)(tn*128 + srow + 16)*p.ldb + swz;

  const int kpseg = p.K >> 5;
  const int nt = kpseg * NSEG;

  auto stage = [&](int step, int buf){
    const int seg = (NSEG==1) ? 0 : (step / kpseg);
    const int k0 = (step - seg*kpseg) << 5;
    const unsigned short* ga = p.Aseg[seg] + zoffA;
    const unsigned short* gb = p.Bseg[seg] + zoffB;
    gload16(ga + aoff0 + k0, &As[buf][w*1024]);
    gload16(ga + aoff1 + k0, &As[buf][w*1024+512]);
    gload16(gb + boff0 + k0, &Bs[buf][w*1024]);
    gload16(gb + boff1 + k0, &Bs[buf][w*1024+512]);
  };

  const int rb = lane & 15, g = lane >> 4;
  const int rswz = (g ^ ((rb>>1)&3)) * 8;

  stage(0, 0);
  __syncthreads();
  int cur = 0;
  for (int s=0; s<nt; ++s){
    if (s+1 < nt) stage(s+1, cur^1);
    bf16x8 af[4], bfr[4];
    #pragma unroll
    for (int m=0;m<4;m++) af[m]  = *(const bf16x8*)&As[cur][(wm*64 + m*16 + rb)*32 + rswz];
    #pragma unroll
    for (int n=0;n<4;n++) bfr[n] = *(const bf16x8*)&Bs[cur][(wn*64 + n*16 + rb)*32 + rswz];
    #pragma unroll
    for (int m=0;m<4;m++)
      #pragma unroll
      for (int n=0;n<4;n++)
        acc[m][n] = __builtin_amdgcn_mfma_f32_16x16x32_bf16(af[m], bfr[n], acc[m][n], 0, 0, 0);
    __syncthreads();
    cur ^= 1;
  }

  const int rl = (lane>>4)*4;
  const int cl = lane & 15;
  const int row0 = tm*128 + wm*64;
  const int col0 = tn*128 + wn*64;
  const float bz = p.bias ? p.bias[z] : 0.0f;
  #pragma unroll
  for (int m=0;m<4;m++)
    #pragma unroll
    for (int n=0;n<4;n++)
      #pragma unroll
      for (int r=0;r<4;r++){
        const int row = row0 + m*16 + rl + r;
        const int col = col0 + n*16 + cl;
        p.Cb[(size_t)z*p.sCb + (size_t)row*p.ldcb + col] = f2bf(p.scale*acc[m][n][r] + bz);
      }
}

// kk-fused output GEMM: for (jj,ii) computes both k=0,1 planes and writes
// interleaved float2 -> fully dense 128B lines (no half-dirty-line RMW).
// WITH_S: out = 0.1*acc + 0.9*S (the "one" branch); else out = acc ("ana", Aan pre-scaled).
struct OutP {
  const unsigned short* Sp;   // S planes, z=j*2+k
  const unsigned short* Bp;   // B planes (A or Aan), z=i*2+k
  float* outp;
};

template<bool WITH_S>
__global__ __launch_bounds__(256,2) void k_out(OutP p){
  const int zi = blockIdx.y;             // 0..15
  const int jj = zi >> 2, ii = zi & 3;
  const int tm = blockIdx.x >> 3, tn = blockIdx.x & 7;
  const unsigned short* A0 = p.Sp + (size_t)(jj*2+0)*NN;
  const unsigned short* A1 = p.Sp + (size_t)(jj*2+1)*NN;
  const unsigned short* B0 = p.Bp + (size_t)(ii*2+0)*NN;
  const unsigned short* B1 = p.Bp + (size_t)(ii*2+1)*NN;
  __shared__ unsigned short As[2][2][4096];
  __shared__ unsigned short Bs[2][2][4096];
  const int t = threadIdx.x;
  const int lane = t & 63;
  const int w = t >> 6;
  const int wm = w >> 1, wn = w & 1;

  f32x4 acc0[4][4], acc1[4][4];
  #pragma unroll
  for (int m=0;m<4;m++)
    #pragma unroll
    for (int n=0;n<4;n++){
      acc0[m][n] = (f32x4)(0.0f);
      acc1[m][n] = (f32x4)(0.0f);
    }

  const int srow = w*32 + (lane>>2);
  const int swz  = ((lane&3) ^ ((srow>>1)&3)) * 8;
  const size_t aoff0 = (size_t)(tm*128 + srow)*1024 + swz;
  const size_t aoff1 = (size_t)(tm*128 + srow + 16)*1024 + swz;
  const size_t boff0 = (size_t)(tn*128 + srow)*1024 + swz;
  const size_t boff1 = (size_t)(tn*128 + srow + 16)*1024 + swz;

  auto stage = [&](int step, int buf){
    const int k0 = step << 5;
    gload16(A0 + aoff0 + k0, &As[buf][0][w*1024]);
    gload16(A0 + aoff1 + k0, &As[buf][0][w*1024+512]);
    gload16(A1 + aoff0 + k0, &As[buf][1][w*1024]);
    gload16(A1 + aoff1 + k0, &As[buf][1][w*1024+512]);
    gload16(B0 + boff0 + k0, &Bs[buf][0][w*1024]);
    gload16(B0 + boff1 + k0, &Bs[buf][0][w*1024+512]);
    gload16(B1 + boff0 + k0, &Bs[buf][1][w*1024]);
    gload16(B1 + boff1 + k0, &Bs[buf][1][w*1024+512]);
  };

  const int rb = lane & 15, g = lane >> 4;
  const int rswz = (g ^ ((rb>>1)&3)) * 8;

  stage(0, 0);
  __syncthreads();
  int cur = 0;
  for (int s=0; s<32; ++s){
    if (s+1 < 32) stage(s+1, cur^1);
    {
      bf16x8 af[4], bfr[4];
      #pragma unroll
      for (int m=0;m<4;m++) af[m]  = *(const bf16x8*)&As[cur][0][(wm*64 + m*16 + rb)*32 + rswz];
      #pragma unroll
      for (int n=0;n<4;n++) bfr[n] = *(const bf16x8*)&Bs[cur][0][(wn*64 + n*16 + rb)*32 + rswz];
      #pragma unroll
      for (int m=0;m<4;m++)
        #pragma unroll
        for (int n=0;n<4;n++)
          acc0[m][n] = __builtin_amdgcn_mfma_f32_16x16x32_bf16(af[m], bfr[n], acc0[m][n], 0, 0, 0);
    }
    {
      bf16x8 af[4], bfr[4];
      #pragma unroll
      for (int m=0;m<4;m++) af[m]  = *(const bf16x8*)&As[cur][1][(wm*64 + m*16 + rb)*32 + rswz];
      #pragma unroll
      for (int n=0;n<4;n++) bfr[n] = *(const bf16x8*)&Bs[cur][1][(wn*64 + n*16 + rb)*32 + rswz];
      #pragma unroll
      for (int m=0;m<4;m++)
        #pragma unroll
        for (int n=0;n<4;n++)
          acc1[m][n] = __builtin_amdgcn_mfma_f32_16x16x32_bf16(af[m], bfr[n], acc1[m][n], 0, 0, 0);
    }
    __syncthreads();
    cur ^= 1;
  }

  const int rl = (lane>>4)*4;
  const int cl = lane & 15;
  const int row0 = tm*128 + wm*64;
  const int col0 = tn*128 + wn*64;
  const size_t ob = (size_t)(jj*4+ii)*(4ull*NN) + (WITH_S ? 0 : 2ull*NN);
  #pragma unroll
  for (int m=0;m<4;m++)
    #pragma unroll
    for (int n=0;n<4;n++)
      #pragma unroll
      for (int r=0;r<4;r++){
        const int row = row0 + m*16 + rl + r;
        const int col = col0 + n*16 + cl;
        float v0 = acc0[m][n][r];
        float v1 = acc1[m][n][r];
        if (WITH_S){
          v0 = 0.1f*v0 + 0.9f*bf2f(A0[(size_t)row*1024 + col]);
          v1 = 0.1f*v1 + 0.9f*bf2f(A1[(size_t)row*1024 + col]);
        }
        float2 val; val.x = v0; val.y = v1;
        *(float2*)(p.outp + ob + ((size_t)row*1024 + col)*2) = val;
      }
}

// ---------------- host ----------------

extern "C" void kernel_launch(void* const* d_in, const int* in_sizes, int n_in,
                              void* d_out, int out_size, void* d_ws, size_t ws_size,
                              hipStream_t stream){
  (void)in_sizes; (void)n_in; (void)out_size; (void)ws_size;
  const float* x  = (const float*)d_in[0];
  const float* Wb = (const float*)d_in[1];
  const float* We = (const float*)d_in[2];
  const float* be = (const float*)d_in[3];
  float* out = (float*)d_out;
  char* ws = (char*)d_ws;

  unsigned short* xhi   = (unsigned short*)(ws + 0);        // 2 MB
  unsigned short* xlo   = (unsigned short*)(ws + 2*MB);     // 2 MB
  unsigned short* wbth  = (unsigned short*)(ws + 4*MB);     // 4 MB
  unsigned short* wbtl  = (unsigned short*)(ws + 8*MB);     // 4 MB
  unsigned short* featb = (unsigned short*)(ws + 12*MB);    // 4 MB
  unsigned short* WT    = (unsigned short*)(ws + 16*MB);    // 4 MB
  unsigned short* Tb    = (unsigned short*)(ws + 20*MB);    // 8 MB
  unsigned short* Sb    = (unsigned short*)(ws + 28*MB);    // 16 MB
  unsigned short* Abuf  = (unsigned short*)(ws + 44*MB);    // 16 MB
  unsigned short* ATb   = (unsigned short*)(ws + 60*MB);    // 16 MB
  unsigned short* A2b   = (unsigned short*)(ws + 76*MB);    // 16 MB
  unsigned short* A3b   = (unsigned short*)(ws + 92*MB);    // 16 MB
  unsigned short* Aan   = (unsigned short*)(ws + 108*MB);   // 16 MB

  // 1. splits / transposes of weights
  k_split_x<<<dim3(1024), dim3(256), 0, stream>>>(x, xhi, xlo);
  k_trans_split<<<dim3(64,32), dim3(32,8), 0, stream>>>(Wb, wbth, wbtl);
  k_wt<<<dim3(16,16,8), dim3(32,8), 0, stream>>>(We, WT);

  // 2. feats = x @ Wb, fused hi/lo split via 3 K-segments
  {
    GemmP q{};
    q.Aseg[0]=xhi; q.Bseg[0]=wbth;
    q.Aseg[1]=xhi; q.Bseg[1]=wbtl;
    q.Aseg[2]=xlo; q.Bseg[2]=wbth;
    q.sA = 0; q.sB = 0; q.zShiftA = 0; q.zShiftB = 0;
    q.lda = 1024; q.ldb = 1024; q.K = 1024; q.tilesN = 16;
    q.Cb = featb; q.sCb = 0; q.ldcb = 2048;
    q.bias = nullptr; q.scale = 1.0f;
    k_gemm<3><<<dim3(8*16,1), dim3(256), 0, stream>>>(q);
  }

  // 3. T[z] = xb_j @ WT_z^T, M=1024 N=512 K=512
  {
    GemmP q{};
    q.Aseg[0] = featb; q.sA = 512; q.zShiftA = 1; q.lda = 2048;
    q.Bseg[0] = WT;    q.sB = (long long)512*512; q.zShiftB = 0; q.ldb = 512;
    q.K = 512; q.tilesN = 4;
    q.Cb = Tb; q.sCb = (long long)1024*512; q.ldcb = 512;
    q.bias = nullptr; q.scale = 1.0f;
    k_gemm<1><<<dim3(8*4,8), dim3(256), 0, stream>>>(q);
  }

  // 4. S[z] = T[z] @ xb_j^T + b_embed[z], M=1024 N=1024 K=512
  {
    GemmP q{};
    q.Aseg[0] = Tb;    q.sA = (long long)1024*512; q.zShiftA = 0; q.lda = 512;
    q.Bseg[0] = featb; q.sB = 512; q.zShiftB = 1; q.ldb = 2048;
    q.K = 512; q.tilesN = 8;
    q.Cb = Sb; q.sCb = (long long)NN; q.ldcb = 1024;
    q.bias = be; q.scale = 1.0f;
    k_gemm<1><<<dim3(8*8,8), dim3(256), 0, stream>>>(q);
  }

  // 5. softmax -> A ; AT = A^T
  k_softmax<<<dim3(1024,8), dim3(256), 0, stream>>>(Sb, Abuf);
  k_transb<<<dim3(16,16,8), dim3(64,4), 0, stream>>>(Abuf, ATb);

  // 6. Neumann (truncated at t=3): A2 = A@A, A3 = A2@A
  auto pgemm = [&](const unsigned short* Aop, unsigned short* dst){
    GemmP q{};
    q.Aseg[0] = Aop; q.sA = (long long)NN; q.zShiftA = 0; q.lda = 1024;
    q.Bseg[0] = ATb; q.sB = (long long)NN; q.zShiftB = 0; q.ldb = 1024;
    q.K = 1024; q.tilesN = 8;
    q.Cb = dst; q.sCb = (long long)NN; q.ldcb = 1024;
    q.bias = nullptr; q.scale = 1.0f;
    k_gemm<1><<<dim3(8*8,8), dim3(256), 0, stream>>>(q);
  };
  pgemm(Abuf, A2b);
  pgemm(A2b,  A3b);

  // 7. Aan = bf16(0.9*(I + 0.1A + 0.01A2 + 0.001A3))
  k_combine<<<dim3(4096), dim3(256), 0, stream>>>(Abuf, A2b, A3b, Aan);

  // 8. one = 0.1*(S_jk @ A_ik^T) + 0.9*S_jk, both kk fused, float2 writes
  {
    OutP q{Sb, Abuf, out};
    k_out<true><<<dim3(64,16), dim3(256), 0, stream>>>(q);
  }
  // 9. ana = S_jk @ Aan_ik^T, both kk fused
  {
    OutP q{Sb, Aan, out};
    k_out<false><<<dim3(64,16), dim3(256), 0, stream>>>(q);
  }
}

// Round 9
// 610.811 us; speedup vs baseline: 1.5012x; 1.0794x over previous
//
#include <hip/hip_runtime.h>

#define NDIM 1024
#define NN (1024ull*1024ull)
#define MB (1ull<<20)

using f32x4  = __attribute__((ext_vector_type(4))) float;
using bf16x8 = __attribute__((ext_vector_type(8))) __bf16;
using u16x8  = __attribute__((ext_vector_type(8))) unsigned short;

__device__ __forceinline__ float bf2f(unsigned short u){
  union{unsigned int i; float f;} x; x.i = ((unsigned int)u)<<16; return x.f;
}
__device__ __forceinline__ unsigned short f2bf(float f){
  union{float fl; unsigned int i;} u; u.fl = f;
  unsigned int x = u.i;
  return (unsigned short)((x + 0x7fffu + ((x>>16)&1u)) >> 16);
}

// async global->LDS, 16B per lane. Dest must be wave-uniform base; HW adds lane*16.
__device__ __forceinline__ void gload16(const unsigned short* g, unsigned short* l){
  __builtin_amdgcn_global_load_lds(
      (const __attribute__((address_space(1))) void*)g,
      (__attribute__((address_space(3))) void*)l,
      16, 0, 0);
}

// ---------------- small kernels ----------------

__global__ void k_split_x(const float* __restrict__ x, unsigned short* __restrict__ hi,
                          unsigned short* __restrict__ lo){
  size_t idx = ((size_t)blockIdx.x*256 + threadIdx.x)*4;
  float4 v = *(const float4*)(x+idx);
  float vv[4] = {v.x, v.y, v.z, v.w};
  ushort4 h, l;
  unsigned short* hp = (unsigned short*)&h;
  unsigned short* lp = (unsigned short*)&l;
  #pragma unroll
  for (int s=0;s<4;s++){
    unsigned short hb = f2bf(vv[s]);
    hp[s] = hb;
    lp[s] = f2bf(vv[s] - bf2f(hb));
  }
  *(ushort4*)(hi+idx) = h;
  *(ushort4*)(lo+idx) = l;
}

__global__ void k_trans_split(const float* __restrict__ Wb, unsigned short* __restrict__ hi,
                              unsigned short* __restrict__ lo){
  __shared__ float t[32][33];
  int bd = blockIdx.x, bc = blockIdx.y;
  int tx = threadIdx.x, ty = threadIdx.y;
  #pragma unroll
  for (int r=0;r<4;r++){
    int c = bc*32 + ty + r*8;
    t[ty+r*8][tx] = Wb[(size_t)c*2048 + bd*32 + tx];
  }
  __syncthreads();
  #pragma unroll
  for (int r=0;r<4;r++){
    int d = bd*32 + ty + r*8, c = bc*32 + tx;
    float v = t[tx][ty+r*8];
    unsigned short h = f2bf(v);
    hi[(size_t)d*1024 + c] = h;
    lo[(size_t)d*1024 + c] = f2bf(v - bf2f(h));
  }
}

__global__ void k_wt(const float* __restrict__ W, unsigned short* __restrict__ WT){
  __shared__ float t[32][33];
  int z = blockIdx.z; int j = z>>1, k = z&1;
  int bd = blockIdx.x, bc = blockIdx.y;
  int tx = threadIdx.x, ty = threadIdx.y;
  #pragma unroll
  for (int r=0;r<4;r++){
    int c = bc*32 + ty + r*8, d = bd*32 + tx;
    t[ty+r*8][tx] = W[(((size_t)j*512 + c)*512 + d)*2 + k];
  }
  __syncthreads();
  #pragma unroll
  for (int r=0;r<4;r++){
    int d = bd*32 + ty + r*8, c = bc*32 + tx;
    WT[((size_t)z*512 + d)*512 + c] = f2bf(t[tx][ty+r*8]);
  }
}

__global__ void k_softmax(const unsigned short* __restrict__ S, unsigned short* __restrict__ A){
  int z = blockIdx.y, c = blockIdx.x, t = threadIdx.x;
  const unsigned short* row = S + ((size_t)z*NDIM + c)*NDIM;
  __shared__ float red[256];
  float v[4];
  float mx = -1e30f;
  #pragma unroll
  for (int s=0;s<4;s++){
    int b = t + s*256;
    float x = bf2f(row[b]);
    if (b==c) x = -1e30f;
    v[s] = x; mx = fmaxf(mx, x);
  }
  red[t]=mx; __syncthreads();
  for (int o=128;o>0;o>>=1){ if (t<o) red[t]=fmaxf(red[t],red[t+o]); __syncthreads(); }
  mx = red[0]; __syncthreads();
  float e[4]; float sum=0.f;
  #pragma unroll
  for (int s=0;s<4;s++){ e[s] = __expf(v[s]-mx); sum += e[s]; }
  red[t]=sum; __syncthreads();
  for (int o=128;o>0;o>>=1){ if (t<o) red[t]+=red[t+o]; __syncthreads(); }
  sum = red[0];
  float inv = 1.0f/sum;
  unsigned short* Ar = A + ((size_t)z*NDIM + c)*NDIM;
  #pragma unroll
  for (int s=0;s<4;s++){
    int b = t + s*256;
    Ar[b] = f2bf(e[s]*inv);
  }
}

__global__ void k_transb(const unsigned short* __restrict__ A, unsigned short* __restrict__ AT){
  __shared__ unsigned short t[64][65];
  int z = blockIdx.z, bb = blockIdx.x, bc = blockIdx.y;
  int tx = threadIdx.x, ty = threadIdx.y; // (64,4)
  const unsigned short* Az = A + (size_t)z*NN;
  #pragma unroll
  for (int r=0;r<16;r++){
    int c = bc*64 + ty + r*4;
    t[ty+r*4][tx] = Az[(size_t)c*NDIM + bb*64 + tx];
  }
  __syncthreads();
  unsigned short* Tz = AT + (size_t)z*NN;
  #pragma unroll
  for (int r=0;r<16;r++){
    int b = bb*64 + ty + r*4;
    Tz[(size_t)b*NDIM + bc*64 + tx] = t[tx][ty+r*4];
  }
}

// Aan = bf16(0.9*(I + 0.1*A + 0.01*A2 + 0.001*A3))
__global__ void k_combine(const unsigned short* __restrict__ A, const unsigned short* __restrict__ A2,
                          const unsigned short* __restrict__ A3, unsigned short* __restrict__ Aan){
  size_t idx = ((size_t)blockIdx.x*256 + threadIdx.x)*8;
  int cb = (int)(idx & (NN - 1));
  int c = cb >> 10, b0 = cb & 1023;
  u16x8 a  = *(const u16x8*)(A+idx);
  u16x8 a2 = *(const u16x8*)(A2+idx);
  u16x8 a3 = *(const u16x8*)(A3+idx);
  u16x8 o;
  #pragma unroll
  for (int s=0;s<8;s++){
    float v = 0.1f*bf2f(a[s]) + 0.01f*bf2f(a2[s]) + 0.001f*bf2f(a3[s]);
    if (b0+s == c) v += 1.0f;
    o[s] = f2bf(0.9f*v);
  }
  *(u16x8*)(Aan+idx) = o;
}

// ---------------- generic 128x128 2-phase GEMM (unchanged) ----------------

struct GemmP {
  const unsigned short* Aseg[3]; const unsigned short* Bseg[3];
  long long sA, sB;
  int zShiftA, zShiftB;
  int lda, ldb;
  int K, tilesN;
  unsigned short* Cb; long long sCb; int ldcb;
  const float* bias;
  float scale;
};

template<int NSEG>
__global__ __launch_bounds__(256) void k_gemm(GemmP p){
  const int z = blockIdx.y;
  const int tm = blockIdx.x / p.tilesN;
  const int tn = blockIdx.x % p.tilesN;
  const size_t zoffA = (size_t)(z>>p.zShiftA)*(size_t)p.sA;
  const size_t zoffB = (size_t)(z>>p.zShiftB)*(size_t)p.sB;
  __shared__ unsigned short As[2][4096];
  __shared__ unsigned short Bs[2][4096];
  const int t = threadIdx.x;
  const int lane = t & 63;
  const int w = t >> 6;
  const int wm = w >> 1, wn = w & 1;

  f32x4 acc[4][4];
  #pragma unroll
  for (int m=0;m<4;m++)
    #pragma unroll
    for (int n=0;n<4;n++)
      acc[m][n] = (f32x4)(0.0f);

  const int srow = w*32 + (lane>>2);
  const int swz  = ((lane&3) ^ ((srow>>1)&3)) * 8;
  const size_t aoff0 = (size_t)(tm*128 + srow)*p.lda + swz;
  const size_t aoff1 = (size_t)(tm*128 + srow + 16)*p.lda + swz;
  const size_t boff0 = (size_t)(tn*128 + srow)*p.ldb + swz;
  const size_t boff1 = (size_t)(tn*128 + srow + 16)*p.ldb + swz;

  const int kpseg = p.K >> 5;
  const int nt = kpseg * NSEG;

  auto stage = [&](int step, int buf){
    const int seg = (NSEG==1) ? 0 : (step / kpseg);
    const int k0 = (step - seg*kpseg) << 5;
    const unsigned short* ga = p.Aseg[seg] + zoffA;
    const unsigned short* gb = p.Bseg[seg] + zoffB;
    gload16(ga + aoff0 + k0, &As[buf][w*1024]);
    gload16(ga + aoff1 + k0, &As[buf][w*1024+512]);
    gload16(gb + boff0 + k0, &Bs[buf][w*1024]);
    gload16(gb + boff1 + k0, &Bs[buf][w*1024+512]);
  };

  const int rb = lane & 15, g = lane >> 4;
  const int rswz = (g ^ ((rb>>1)&3)) * 8;

  stage(0, 0);
  __syncthreads();
  int cur = 0;
  for (int s=0; s<nt; ++s){
    if (s+1 < nt) stage(s+1, cur^1);
    bf16x8 af[4], bfr[4];
    #pragma unroll
    for (int m=0;m<4;m++) af[m]  = *(const bf16x8*)&As[cur][(wm*64 + m*16 + rb)*32 + rswz];
    #pragma unroll
    for (int n=0;n<4;n++) bfr[n] = *(const bf16x8*)&Bs[cur][(wn*64 + n*16 + rb)*32 + rswz];
    #pragma unroll
    for (int m=0;m<4;m++)
      #pragma unroll
      for (int n=0;n<4;n++)
        acc[m][n] = __builtin_amdgcn_mfma_f32_16x16x32_bf16(af[m], bfr[n], acc[m][n], 0, 0, 0);
    __syncthreads();
    cur ^= 1;
  }

  const int rl = (lane>>4)*4;
  const int cl = lane & 15;
  const int row0 = tm*128 + wm*64;
  const int col0 = tn*128 + wn*64;
  const float bz = p.bias ? p.bias[z] : 0.0f;
  #pragma unroll
  for (int m=0;m<4;m++)
    #pragma unroll
    for (int n=0;n<4;n++)
      #pragma unroll
      for (int r=0;r<4;r++){
        const int row = row0 + m*16 + rl + r;
        const int col = col0 + n*16 + cl;
        p.Cb[(size_t)z*p.sCb + (size_t)row*p.ldcb + col] = f2bf(p.scale*acc[m][n][r] + bz);
      }
}

// ---------------- 256x128 kk-fused output GEMM, counted-vmcnt 2-buf pipeline ----------------
// 512 threads = 8 waves (4M x 2N); per-wave 64x64 output per kk plane.
// LDS: 2 buf x 2 kk x (A 256x32 + B 128x32) bf16 = 96 KB -> 1 block/CU, 2 waves/SIMD.
// Per stage per wave: 6 global_load_lds. Counted s_waitcnt vmcnt(6) keeps the next
// stage in flight across the barrier (T4); raw s_barrier; sched_barrier(0) fences:
// (a) after top barrier: ds_reads can't hoist above it; (b) after bottom barrier:
// next iteration's stage (LDS write) can't hoist above it (raw s_barrier is not a
// compiler memory fence -- this pins the stage/read ordering explicitly).

struct OutP {
  const unsigned short* Sp;   // S planes, z=j*2+k
  const unsigned short* Bp;   // B planes (A or Aan), z=i*2+k
  float* outp;
};

template<bool WITH_S>
__global__ __launch_bounds__(512,2) void k_out(OutP p){
  const int zi = blockIdx.y;             // 0..15
  const int jj = zi >> 2, ii = zi & 3;
  // same-XCD grouping: XCD = blockIdx.x % 8; tm = blockIdx.x & 3 is constant per XCD
  // -> the 4 blocks on one XCD share the same A panel.
  const int tm = blockIdx.x & 3;         // 0..3 (256-row panels)
  const int tn = blockIdx.x >> 2;        // 0..7 (128-col panels)
  const unsigned short* A0 = p.Sp + (size_t)(jj*2+0)*NN;
  const unsigned short* A1 = p.Sp + (size_t)(jj*2+1)*NN;
  const unsigned short* B0 = p.Bp + (size_t)(ii*2+0)*NN;
  const unsigned short* B1 = p.Bp + (size_t)(ii*2+1)*NN;
  __shared__ unsigned short sm[49152];   // [buf][kk][A 8192 | B 4096] shorts
  const int t = threadIdx.x;
  const int lane = t & 63;
  const int w = t >> 6;                  // 0..7
  const int wr = w >> 1, wc = w & 1;

  f32x4 acc0[4][4], acc1[4][4];
  #pragma unroll
  for (int m=0;m<4;m++)
    #pragma unroll
    for (int n=0;n<4;n++){
      acc0[m][n] = (f32x4)(0.0f);
      acc1[m][n] = (f32x4)(0.0f);
    }

  // staging geometry (per wave): A call c in {0,1}: row = c*128 + w*16 + (lane>>2),
  // B: row = w*16 + (lane>>2). chunk = (lane&3) ^ ((row>>1)&3)  (involution).
  const int lrow = w*16 + (lane>>2);
  const int rowA0 = lrow, rowA1 = 128 + lrow, rowB = lrow;
  const int chA0 = ((lane&3) ^ ((rowA0>>1)&3)) * 8;
  const int chA1 = ((lane&3) ^ ((rowA1>>1)&3)) * 8;
  const int chB  = ((lane&3) ^ ((rowB>>1)&3)) * 8;
  const size_t aoffc0 = (size_t)(tm*256 + rowA0)*1024 + chA0;
  const size_t aoffc1 = (size_t)(tm*256 + rowA1)*1024 + chA1;
  const size_t boff   = (size_t)(tn*128 + rowB)*1024 + chB;
  const int wslot = w*512;               // shorts; lane slot = lane*8 within

  auto stage = [&](int step, int buf){
    const int k0 = step << 5;
    unsigned short* r0 = &sm[(buf*2+0)*12288];
    unsigned short* r1 = &sm[(buf*2+1)*12288];
    gload16(A0 + aoffc0 + k0, r0 + wslot);
    gload16(A0 + aoffc1 + k0, r0 + 4096 + wslot);
    gload16(B0 + boff   + k0, r0 + 8192 + wslot);
    gload16(A1 + aoffc0 + k0, r1 + wslot);
    gload16(A1 + aoffc1 + k0, r1 + 4096 + wslot);
    gload16(B1 + boff   + k0, r1 + 8192 + wslot);
  };

  const int rb = lane & 15, g = lane >> 4;
  const int rswz = (g ^ ((rb>>1)&3)) * 8;

  stage(0, 0);
  int cur = 0;
  for (int s=0; s<32; ++s){
    if (s+1 < 32){
      stage(s+1, cur^1);
      asm volatile("s_waitcnt vmcnt(6)" ::: "memory");
    } else {
      asm volatile("s_waitcnt vmcnt(0)" ::: "memory");
    }
    __builtin_amdgcn_s_barrier();
    __builtin_amdgcn_sched_barrier(0);
    const unsigned short* r0 = &sm[(cur*2+0)*12288];
    const unsigned short* r1 = &sm[(cur*2+1)*12288];
    bf16x8 af0[4], bf0[4], af1[4], bf1[4];
    #pragma unroll
    for (int m=0;m<4;m++){
      af0[m] = *(const bf16x8*)(r0 + (wr*64 + m*16 + rb)*32 + rswz);
      af1[m] = *(const bf16x8*)(r1 + (wr*64 + m*16 + rb)*32 + rswz);
    }
    #pragma unroll
    for (int n=0;n<4;n++){
      bf0[n] = *(const bf16x8*)(r0 + 8192 + (wc*64 + n*16 + rb)*32 + rswz);
      bf1[n] = *(const bf16x8*)(r1 + 8192 + (wc*64 + n*16 + rb)*32 + rswz);
    }
    __builtin_amdgcn_s_setprio(1);
    #pragma unroll
    for (int m=0;m<4;m++)
      #pragma unroll
      for (int n=0;n<4;n++){
        acc0[m][n] = __builtin_amdgcn_mfma_f32_16x16x32_bf16(af0[m], bf0[n], acc0[m][n], 0, 0, 0);
        acc1[m][n] = __builtin_amdgcn_mfma_f32_16x16x32_bf16(af1[m], bf1[n], acc1[m][n], 0, 0, 0);
      }
    __builtin_amdgcn_s_setprio(0);
    __builtin_amdgcn_sched_barrier(0);
    __builtin_amdgcn_s_barrier();
    __builtin_amdgcn_sched_barrier(0);   // pin next iter's stage AFTER this barrier
    cur ^= 1;
  }

  const int rl = (lane>>4)*4;
  const int cl = lane & 15;
  const int row0 = tm*256 + wr*64;
  const int col0 = tn*128 + wc*64;
  const size_t ob = (size_t)(jj*4+ii)*(4ull*NN) + (WITH_S ? 0 : 2ull*NN);
  #pragma unroll
  for (int m=0;m<4;m++)
    #pragma unroll
    for (int n=0;n<4;n++)
      #pragma unroll
      for (int r=0;r<4;r++){
        const int row = row0 + m*16 + rl + r;
        const int col = col0 + n*16 + cl;
        float v0 = acc0[m][n][r];
        float v1 = acc1[m][n][r];
        if (WITH_S){
          v0 = 0.1f*v0 + 0.9f*bf2f(A0[(size_t)row*1024 + col]);
          v1 = 0.1f*v1 + 0.9f*bf2f(A1[(size_t)row*1024 + col]);
        }
        float2 val; val.x = v0; val.y = v1;
        *(float2*)(p.outp + ob + ((size_t)row*1024 + col)*2) = val;
      }
}

// ---------------- host ----------------

extern "C" void kernel_launch(void* const* d_in, const int* in_sizes, int n_in,
                              void* d_out, int out_size, void* d_ws, size_t ws_size,
                              hipStream_t stream){
  (void)in_sizes; (void)n_in; (void)out_size; (void)ws_size;
  const float* x  = (const float*)d_in[0];
  const float* Wb = (const float*)d_in[1];
  const float* We = (const float*)d_in[2];
  const float* be = (const float*)d_in[3];
  float* out = (float*)d_out;
  char* ws = (char*)d_ws;

  unsigned short* xhi   = (unsigned short*)(ws + 0);        // 2 MB
  unsigned short* xlo   = (unsigned short*)(ws + 2*MB);     // 2 MB
  unsigned short* wbth  = (unsigned short*)(ws + 4*MB);     // 4 MB
  unsigned short* wbtl  = (unsigned short*)(ws + 8*MB);     // 4 MB
  unsigned short* featb = (unsigned short*)(ws + 12*MB);    // 4 MB
  unsigned short* WT    = (unsigned short*)(ws + 16*MB);    // 4 MB
  unsigned short* Tb    = (unsigned short*)(ws + 20*MB);    // 8 MB
  unsigned short* Sb    = (unsigned short*)(ws + 28*MB);    // 16 MB
  unsigned short* Abuf  = (unsigned short*)(ws + 44*MB);    // 16 MB
  unsigned short* ATb   = (unsigned short*)(ws + 60*MB);    // 16 MB
  unsigned short* A2b   = (unsigned short*)(ws + 76*MB);    // 16 MB
  unsigned short* A3b   = (unsigned short*)(ws + 92*MB);    // 16 MB
  unsigned short* Aan   = (unsigned short*)(ws + 108*MB);   // 16 MB

  // 1. splits / transposes of weights
  k_split_x<<<dim3(1024), dim3(256), 0, stream>>>(x, xhi, xlo);
  k_trans_split<<<dim3(64,32), dim3(32,8), 0, stream>>>(Wb, wbth, wbtl);
  k_wt<<<dim3(16,16,8), dim3(32,8), 0, stream>>>(We, WT);

  // 2. feats = x @ Wb, fused hi/lo split via 3 K-segments
  {
    GemmP q{};
    q.Aseg[0]=xhi; q.Bseg[0]=wbth;
    q.Aseg[1]=xhi; q.Bseg[1]=wbtl;
    q.Aseg[2]=xlo; q.Bseg[2]=wbth;
    q.sA = 0; q.sB = 0; q.zShiftA = 0; q.zShiftB = 0;
    q.lda = 1024; q.ldb = 1024; q.K = 1024; q.tilesN = 16;
    q.Cb = featb; q.sCb = 0; q.ldcb = 2048;
    q.bias = nullptr; q.scale = 1.0f;
    k_gemm<3><<<dim3(8*16,1), dim3(256), 0, stream>>>(q);
  }

  // 3. T[z] = xb_j @ WT_z^T, M=1024 N=512 K=512
  {
    GemmP q{};
    q.Aseg[0] = featb; q.sA = 512; q.zShiftA = 1; q.lda = 2048;
    q.Bseg[0] = WT;    q.sB = (long long)512*512; q.zShiftB = 0; q.ldb = 512;
    q.K = 512; q.tilesN = 4;
    q.Cb = Tb; q.sCb = (long long)1024*512; q.ldcb = 512;
    q.bias = nullptr; q.scale = 1.0f;
    k_gemm<1><<<dim3(8*4,8), dim3(256), 0, stream>>>(q);
  }

  // 4. S[z] = T[z] @ xb_j^T + b_embed[z], M=1024 N=1024 K=512
  {
    GemmP q{};
    q.Aseg[0] = Tb;    q.sA = (long long)1024*512; q.zShiftA = 0; q.lda = 512;
    q.Bseg[0] = featb; q.sB = 512; q.zShiftB = 1; q.ldb = 2048;
    q.K = 512; q.tilesN = 8;
    q.Cb = Sb; q.sCb = (long long)NN; q.ldcb = 1024;
    q.bias = be; q.scale = 1.0f;
    k_gemm<1><<<dim3(8*8,8), dim3(256), 0, stream>>>(q);
  }

  // 5. softmax -> A ; AT = A^T
  k_softmax<<<dim3(1024,8), dim3(256), 0, stream>>>(Sb, Abuf);
  k_transb<<<dim3(16,16,8), dim3(64,4), 0, stream>>>(Abuf, ATb);

  // 6. Neumann (truncated at t=3): A2 = A@A, A3 = A2@A
  auto pgemm = [&](const unsigned short* Aop, unsigned short* dst){
    GemmP q{};
    q.Aseg[0] = Aop; q.sA = (long long)NN; q.zShiftA = 0; q.lda = 1024;
    q.Bseg[0] = ATb; q.sB = (long long)NN; q.zShiftB = 0; q.ldb = 1024;
    q.K = 1024; q.tilesN = 8;
    q.Cb = dst; q.sCb = (long long)NN; q.ldcb = 1024;
    q.bias = nullptr; q.scale = 1.0f;
    k_gemm<1><<<dim3(8*8,8), dim3(256), 0, stream>>>(q);
  };
  pgemm(Abuf, A2b);
  pgemm(A2b,  A3b);

  // 7. Aan = bf16(0.9*(I + 0.1A + 0.01A2 + 0.001A3))
  k_combine<<<dim3(4096), dim3(256), 0, stream>>>(Abuf, A2b, A3b, Aan);

  // 8. one = 0.1*(S_jk @ A_ik^T) + 0.9*S_jk, both kk fused, float2 writes
  {
    OutP q{Sb, Abuf, out};
    k_out<true><<<dim3(32,16), dim3(512), 0, stream>>>(q);
  }
  // 9. ana = S_jk @ Aan_ik^T, both kk fused
  {
    OutP q{Sb, Aan, out};
    k_out<false><<<dim3(32,16), dim3(512), 0, stream>>>(q);
  }
}